// Round 3
// baseline (3354.975 us; speedup 1.0000x reference)
//
#include <hip/hip_runtime.h>

#define N_Q   65536
#define N_C   2048
#define KNN_K 16
#define CDIM  64

// ---------------------------------------------------------------------------
// Kernel 0: transpose/pad fp32 weights -> fp32 [n][k] layouts in ws.
//  T0: 128x128 @ 0       (k==127 -> 0)            W0 is (127,128)
//  T1: 128x128 @ 16384                            W1 is (128,128)
//  T2: 128x256 @ 32768   (k==127 -> 0, k>=128 -> W2[k-1])   W2 is (255,128)
//  T3: 128x128 @ 65536                            W3 is (128,128)
//  Tf: 128x128 @ 81920                            Wf is (128,128)
//  Td:  64x160 @ 98304   (k>=155 -> 0)            Wd is (155,64)
//  Ts: 128     @ 108544                           Ws is (128,1)
//  Tr: 3x64    @ 108672  (Tr[c][k] = Wr[k][c])    Wr is (64,3)
// total 108864 floats
// ---------------------------------------------------------------------------
__global__ void wtrans_kernel(const float* W0, const float* W1, const float* W2,
                              const float* W3, const float* Wf, const float* Wd,
                              const float* Ws, const float* Wr, float* wt){
  int idx = blockIdx.x * 256 + threadIdx.x;
  if (idx >= 108864) return;
  float val;
  if (idx < 16384){
    int i = idx, n = i >> 7, k = i & 127;
    val = (k < 127) ? W0[k*128 + n] : 0.f;
  } else if (idx < 32768){
    int i = idx - 16384, n = i >> 7, k = i & 127;
    val = W1[k*128 + n];
  } else if (idx < 65536){
    int i = idx - 32768, n = i >> 8, k = i & 255;
    val = (k == 127) ? 0.f : ((k < 127) ? W2[k*128 + n] : W2[(k-1)*128 + n]);
  } else if (idx < 81920){
    int i = idx - 65536, n = i >> 7, k = i & 127;
    val = W3[k*128 + n];
  } else if (idx < 98304){
    int i = idx - 81920, n = i >> 7, k = i & 127;
    val = Wf[k*128 + n];
  } else if (idx < 108544){
    int i = idx - 98304, n = i / 160, k = i - n*160;
    val = (k < 155) ? Wd[k*64 + n] : 0.f;
  } else if (idx < 108672){
    int k = idx - 108544;
    val = Ws[k];
  } else {
    int i = idx - 108672, c = i >> 6, k = i & 63;
    val = Wr[k*3 + c];
  }
  wt[idx] = val;
}

// ---------------------------------------------------------------------------
// Kernel 1: exact 16-NN + inverse-d2 weighted code interpolation (all fp32).
// One wave per query; lane owns candidates c = j*64 + lane, j in [0,32).
// Packed key: (d2_bits & ~0x7FF) | c -> argmin == min, ties -> lower index.
// ---------------------------------------------------------------------------
__global__ __launch_bounds__(256) void knn_kernel(const int* indices,
    const float* qpts, const float* cpos, const float* codes, float* qcw){
  __shared__ float lx[N_C], ly[N_C], lz[N_C];
  int tid = threadIdx.x;
  int lane = tid & 63, wave = tid >> 6;
  int idx0 = indices[0];
  const float* cp = cpos + (size_t)idx0 * N_C * 3;
  const float* cc = codes + (size_t)idx0 * N_C * CDIM;

  for (int c = tid; c < N_C; c += 256){
    lx[c] = cp[c*3 + 0];
    ly[c] = cp[c*3 + 1];
    lz[c] = cp[c*3 + 2];
  }
  __syncthreads();

#pragma unroll 1
  for (int qi = 0; qi < 16; qi++){
    int q = blockIdx.x * 64 + wave * 16 + qi;
    float qx = qpts[q*3 + 0];
    float qy = qpts[q*3 + 1];
    float qz = qpts[q*3 + 2];

    int p[32];
#pragma unroll
    for (int j = 0; j < 32; j++){
      int c = j*64 + lane;
      float dx = qx - lx[c], dy = qy - ly[c], dz = qz - lz[c];
      float d2 = fmaf(dz, dz, fmaf(dy, dy, dx*dx));
      p[j] = (__float_as_int(d2) & 0xFFFFF800) | c;
    }

    int keepv = 0;
#pragma unroll 1
    for (int r = 0; r < KNN_K; r++){
      int lm = p[0];
#pragma unroll
      for (int j = 1; j < 32; j++) lm = min(lm, p[j]);
      int gm = lm;
#pragma unroll
      for (int off = 1; off < 64; off <<= 1)
        gm = min(gm, __shfl_xor(gm, off, 64));
      if (lane == r) keepv = gm;
#pragma unroll
      for (int j = 0; j < 32; j++) p[j] = (p[j] == gm) ? 0x7FFFFFFF : p[j];
    }

    // exact d2 + weight for lanes 0..15
    int ci = keepv & 0x7FF;
    float dx = qx - lx[ci], dy = qy - ly[ci], dz = qz - lz[ci];
    float d2 = fmaf(dz, dz, fmaf(dy, dy, dx*dx));
    float w = 1.0f / (d2 + 1e-16f);
    float wm = (lane < KNN_K) ? w : 0.0f;
#pragma unroll
    for (int off = 1; off < 64; off <<= 1) wm += __shfl_xor(wm, off, 64);
    float wn = w / wm;

    float acc = 0.f;
#pragma unroll
    for (int i = 0; i < KNN_K; i++){
      int   cb = __shfl(ci, i, 64);
      float wb = __shfl(wn, i, 64);
      acc = fmaf(wb, cc[cb*CDIM + lane], acc);
    }
    qcw[(size_t)q*CDIM + lane] = acc;
  }
}

// ---------------------------------------------------------------------------
// Kernel 2: VALU fp32 MLP. 16 queries/block, 256 threads.
// Thread t: query q = t>>4, owns output cols c16+16j (c16 = t&15).
// ---------------------------------------------------------------------------
__device__ inline void gemv_acc(const float* IN, int instride, int q,
                                const float* Wt, int Kstride, int Klen,
                                int c16, int NJ, float* acc){
#pragma unroll 1
  for (int k0 = 0; k0 < Klen; k0 += 4){
    float4 xv = *(const float4*)&IN[q*instride + k0];
#pragma unroll
    for (int j = 0; j < 8; j++){
      if (j >= NJ) break;
      float4 wv = *(const float4*)&Wt[(c16 + 16*j)*Kstride + k0];
      acc[j] = fmaf(xv.x, wv.x, acc[j]);
      acc[j] = fmaf(xv.y, wv.y, acc[j]);
      acc[j] = fmaf(xv.z, wv.z, acc[j]);
      acc[j] = fmaf(xv.w, wv.w, acc[j]);
    }
  }
}

__global__ __launch_bounds__(256) void mlp_valu(
    const float* qcw, const float* xyzdir, const float* wt,
    const float* b0, const float* b1, const float* b2, const float* b3,
    const float* bfb, const float* bdb, const float* bsb, const float* brb,
    float* out){
  __shared__ float X[16*128];   // input_xyz (col 127 = 0); cols 0..63 reused for d
  __shared__ float H[16*128];
  __shared__ float G[16*128];
  __shared__ float D[16*32];    // input_dir padded to 32

  int tid = threadIdx.x;
  int q = tid >> 4, c16 = tid & 15;
  int qbase = blockIdx.x * 16;

  for (int i = tid; i < 16*128; i += 256){
    int r = i >> 7, c = i & 127;
    size_t qq = qbase + r;
    X[i] = (c < 64) ? qcw[qq*64 + c]
         : ((c < 127) ? xyzdir[qq*90 + (c - 64)] : 0.f);
  }
  for (int i = tid; i < 16*32; i += 256){
    int r = i >> 5, c = i & 31;
    D[i] = (c < 27) ? xyzdir[(size_t)(qbase + r)*90 + 63 + c] : 0.f;
  }
  __syncthreads();

  const float* T0 = wt;
  const float* T1 = wt + 16384;
  const float* T2 = wt + 32768;
  const float* T3 = wt + 65536;
  const float* Tf = wt + 81920;
  const float* Td = wt + 98304;
  const float* Ts = wt + 108544;
  const float* Tr = wt + 108672;

  float acc[8];

  // L0: h0 = relu(X @ W0 + b0) -> H
#pragma unroll
  for (int j = 0; j < 8; j++) acc[j] = b0[c16 + 16*j];
  gemv_acc(X, 128, q, T0, 128, 128, c16, 8, acc);
#pragma unroll
  for (int j = 0; j < 8; j++) H[q*128 + c16 + 16*j] = fmaxf(acc[j], 0.f);
  __syncthreads();

  // L1: h1 = relu(H @ W1 + b1) -> G
#pragma unroll
  for (int j = 0; j < 8; j++) acc[j] = b1[c16 + 16*j];
  gemv_acc(H, 128, q, T1, 128, 128, c16, 8, acc);
#pragma unroll
  for (int j = 0; j < 8; j++) G[q*128 + c16 + 16*j] = fmaxf(acc[j], 0.f);
  __syncthreads();

  // L2: h2 = relu([input_xyz | h1] @ W2 + b2) -> H   (K = 256)
#pragma unroll
  for (int j = 0; j < 8; j++) acc[j] = b2[c16 + 16*j];
  gemv_acc(X, 128, q, T2,       256, 128, c16, 8, acc);
  gemv_acc(G, 128, q, T2 + 128, 256, 128, c16, 8, acc);
#pragma unroll
  for (int j = 0; j < 8; j++) H[q*128 + c16 + 16*j] = fmaxf(acc[j], 0.f);
  __syncthreads();

  // L3: h3 = relu(H @ W3 + b3) -> G  (kept for sigma)
#pragma unroll
  for (int j = 0; j < 8; j++) acc[j] = b3[c16 + 16*j];
  gemv_acc(H, 128, q, T3, 128, 128, c16, 8, acc);
#pragma unroll
  for (int j = 0; j < 8; j++) G[q*128 + c16 + 16*j] = fmaxf(acc[j], 0.f);
  __syncthreads();

  // Lf: final = G @ Wf + bf (no relu) -> H
#pragma unroll
  for (int j = 0; j < 8; j++) acc[j] = bfb[c16 + 16*j];
  gemv_acc(G, 128, q, Tf, 128, 128, c16, 8, acc);
#pragma unroll
  for (int j = 0; j < 8; j++) H[q*128 + c16 + 16*j] = acc[j];
  __syncthreads();

  // Ld: d = relu([final | input_dir] @ Wd + bd) -> X[:, 0:64]
#pragma unroll
  for (int j = 0; j < 4; j++) acc[j] = bdb[c16 + 16*j];
  gemv_acc(H, 128, q, Td,       160, 128, c16, 4, acc);
  gemv_acc(D,  32, q, Td + 128, 160,  32, c16, 4, acc);
  __syncthreads();
#pragma unroll
  for (int j = 0; j < 4; j++) X[q*128 + c16 + 16*j] = fmaxf(acc[j], 0.f);
  __syncthreads();

  // Tail: sigma = h3(G) . Ws + bs ; rgb = d(X) . Wr + br
  {
    int part = c16;
    float s = 0.f;
#pragma unroll
    for (int k = 0; k < 8; k++){
      int kk = part*8 + k;
      s = fmaf(G[q*128 + kk], Ts[kk], s);
    }
    s += __shfl_xor(s, 1, 64); s += __shfl_xor(s, 2, 64);
    s += __shfl_xor(s, 4, 64); s += __shfl_xor(s, 8, 64);

    float r3[3];
#pragma unroll
    for (int c2 = 0; c2 < 3; c2++){
      float rv = 0.f;
#pragma unroll
      for (int k = 0; k < 4; k++){
        int kk = part*4 + k;
        rv = fmaf(X[q*128 + kk], Tr[c2*64 + kk], rv);
      }
      rv += __shfl_xor(rv, 1, 64); rv += __shfl_xor(rv, 2, 64);
      rv += __shfl_xor(rv, 4, 64); rv += __shfl_xor(rv, 8, 64);
      r3[c2] = rv;
    }
    if (part == 0){
      size_t ob = ((size_t)(qbase + q)) * 4;
      out[ob + 0] = r3[0] + brb[0];
      out[ob + 1] = r3[1] + brb[1];
      out[ob + 2] = r3[2] + brb[2];
      out[ob + 3] = s + bsb[0];
    }
  }
}

// ---------------------------------------------------------------------------
extern "C" void kernel_launch(void* const* d_in, const int* in_sizes, int n_in,
                              void* d_out, int out_size, void* d_ws, size_t ws_size,
                              hipStream_t stream){
  (void)in_sizes; (void)n_in; (void)out_size; (void)ws_size;

  const int*   indices = (const int*)d_in[0];
  const float* qpts    = (const float*)d_in[1];
  const float* xyzdir  = (const float*)d_in[2];
  const float* cpos    = (const float*)d_in[3];
  const float* codes   = (const float*)d_in[4];
  const float* W0 = (const float*)d_in[5];
  const float* b0 = (const float*)d_in[6];
  const float* W1 = (const float*)d_in[7];
  const float* b1 = (const float*)d_in[8];
  const float* W2 = (const float*)d_in[9];
  const float* b2 = (const float*)d_in[10];
  const float* W3 = (const float*)d_in[11];
  const float* b3 = (const float*)d_in[12];
  const float* Wf = (const float*)d_in[13];
  const float* bf = (const float*)d_in[14];
  const float* Wd = (const float*)d_in[15];
  const float* bd = (const float*)d_in[16];
  const float* Ws = (const float*)d_in[17];
  const float* bs = (const float*)d_in[18];
  const float* Wr = (const float*)d_in[19];
  const float* br = (const float*)d_in[20];

  float* qcw = (float*)d_ws;                                  // 65536*64 fp32 = 16 MB
  float* wt  = (float*)((char*)d_ws + (size_t)N_Q*CDIM*4);    // 108864 fp32

  wtrans_kernel<<<(108864 + 255)/256, 256, 0, stream>>>(W0, W1, W2, W3, Wf, Wd, Ws, Wr, wt);
  knn_kernel<<<N_Q/64, 256, 0, stream>>>(indices, qpts, cpos, codes, qcw);
  mlp_valu<<<N_Q/16, 256, 0, stream>>>(qcw, xyzdir, wt,
                                       b0, b1, b2, b3, bf, bd, bs, br,
                                       (float*)d_out);
}

// Round 4
// 507.707 us; speedup vs baseline: 6.6081x; 6.6081x over previous
//
#include <hip/hip_runtime.h>

#define N_Q   65536
#define N_C   2048
#define KNN_K 16
#define CDIM  64

typedef _Float16 half_t;
typedef float v4f __attribute__((ext_vector_type(4)));
typedef half_t v8h __attribute__((ext_vector_type(8)));

#define ASTRIDE 136   // 128 + 8 pad (halves); row = 272 B = 17*16 B
#define DSTRIDE 40    // 32 + 8 pad

// ---------------------------------------------------------------------------
// Kernel 0: transpose/pad fp32 weights -> fp16 [n][k] layouts in ws.
//  wt0 : 128n x 128k  (k==127 -> 0)                       @ 0
//  wt1 : 128n x 128k                                      @ 16384
//  wt2 : 128n x 256k  (k==127 -> 0, k>=128 -> W2[k-1])    @ 32768
//  wt3 : 128n x 128k                                      @ 65536
//  wtf : 128n x 128k                                      @ 81920
//  wtd :  64n x 160k  (k>=155 -> 0)                       @ 98304
// total 108544 halves
// ---------------------------------------------------------------------------
__global__ void wtrans_kernel(const float* W0, const float* W1, const float* W2,
                              const float* W3, const float* Wf, const float* Wd,
                              half_t* wt){
  int idx = blockIdx.x * 256 + threadIdx.x;
  if (idx >= 108544) return;
  float val;
  if (idx < 16384){
    int i = idx, n = i >> 7, k = i & 127;
    val = (k < 127) ? W0[k*128 + n] : 0.f;
  } else if (idx < 32768){
    int i = idx - 16384, n = i >> 7, k = i & 127;
    val = W1[k*128 + n];
  } else if (idx < 65536){
    int i = idx - 32768, n = i >> 8, k = i & 255;
    val = (k == 127) ? 0.f : ((k < 127) ? W2[k*128 + n] : W2[(k-1)*128 + n]);
  } else if (idx < 81920){
    int i = idx - 65536, n = i >> 7, k = i & 127;
    val = W3[k*128 + n];
  } else if (idx < 98304){
    int i = idx - 81920, n = i >> 7, k = i & 127;
    val = Wf[k*128 + n];
  } else {
    int i = idx - 98304, n = i / 160, k = i - n*160;
    val = (k < 155) ? Wd[k*64 + n] : 0.f;
  }
  wt[idx] = (half_t)val;
}

// ---------------------------------------------------------------------------
// Kernel 1: exact 16-NN + inverse-d2 weighted code interpolation (fp32).
// One wave per query; lane owns candidates c = j*64 + lane, j in [0,32).
// Packed key: (d2_bits & ~0x7FF) | c -> argmin == min, ties -> lower index.
// ---------------------------------------------------------------------------
__global__ __launch_bounds__(256) void knn_kernel(const int* indices,
    const float* qpts, const float* cpos, const float* codes, float* qcw){
  __shared__ float lx[N_C], ly[N_C], lz[N_C];
  int tid = threadIdx.x;
  int lane = tid & 63, wave = tid >> 6;
  int idx0 = indices[0];
  const float* cp = cpos + (size_t)idx0 * N_C * 3;
  const float* cc = codes + (size_t)idx0 * N_C * CDIM;

  for (int c = tid; c < N_C; c += 256){
    lx[c] = cp[c*3 + 0];
    ly[c] = cp[c*3 + 1];
    lz[c] = cp[c*3 + 2];
  }
  __syncthreads();

#pragma unroll 1
  for (int qi = 0; qi < 16; qi++){
    int q = blockIdx.x * 64 + wave * 16 + qi;
    float qx = qpts[q*3 + 0];
    float qy = qpts[q*3 + 1];
    float qz = qpts[q*3 + 2];

    int p[32];
#pragma unroll
    for (int j = 0; j < 32; j++){
      int c = j*64 + lane;
      float dx = qx - lx[c], dy = qy - ly[c], dz = qz - lz[c];
      float d2 = fmaf(dz, dz, fmaf(dy, dy, dx*dx));
      p[j] = (__float_as_int(d2) & 0xFFFFF800) | c;
    }

    int keepv = 0;
#pragma unroll 1
    for (int r = 0; r < KNN_K; r++){
      int lm = p[0];
#pragma unroll
      for (int j = 1; j < 32; j++) lm = min(lm, p[j]);
      int gm = lm;
#pragma unroll
      for (int off = 1; off < 64; off <<= 1)
        gm = min(gm, __shfl_xor(gm, off, 64));
      if (lane == r) keepv = gm;
#pragma unroll
      for (int j = 0; j < 32; j++) p[j] = (p[j] == gm) ? 0x7FFFFFFF : p[j];
    }

    int ci = keepv & 0x7FF;
    float dx = qx - lx[ci], dy = qy - ly[ci], dz = qz - lz[ci];
    float d2 = fmaf(dz, dz, fmaf(dy, dy, dx*dx));
    float w = 1.0f / (d2 + 1e-16f);
    float wm = (lane < KNN_K) ? w : 0.0f;
#pragma unroll
    for (int off = 1; off < 64; off <<= 1) wm += __shfl_xor(wm, off, 64);
    float wn = w / wm;

    float acc = 0.f;
#pragma unroll
    for (int i = 0; i < KNN_K; i++){
      int   cb = __shfl(ci, i, 64);
      float wb = __shfl(wn, i, 64);
      acc = fmaf(wb, cc[cb*CDIM + lane], acc);
    }
    qcw[(size_t)q*CDIM + lane] = acc;
  }
}

// ---------------------------------------------------------------------------
// Kernel 2: fused MFMA MLP. 32 queries/block, 256 threads (4 waves).
// wave>>1 -> row half (16 rows), wave&1 -> col half.
// ---------------------------------------------------------------------------
template<int KCH>
__device__ inline void stage_w(const half_t* wg, int Kstride, int k0, int Nout,
                               half_t* WLp, int tid){
  const int kd = KCH >> 1;           // dwords per row
  int tot = Nout * kd;
  for (int i = tid; i < tot; i += 256){
    int n = i / kd, kk = i - n*kd;
    *(unsigned int*)&WLp[n*ASTRIDE + (kk << 1)] =
        *(const unsigned int*)&wg[(size_t)n*Kstride + k0 + (kk << 1)];
  }
}

template<int NT>
__device__ inline void mfma_chunk(const half_t* act, int astride, int rowbase,
                                  int colbase, const half_t* WLp, int kchunk,
                                  v4f* acc, int lane){
  int m = lane & 15, quad = lane >> 4;
#pragma unroll 1
  for (int k0 = 0; k0 < kchunk; k0 += 32){
    v8h a = *(const v8h*)&act[(rowbase + m)*astride + k0 + quad*8];
#pragma unroll
    for (int t = 0; t < NT; t++){
      v8h b = *(const v8h*)&WLp[(colbase + t*16 + m)*ASTRIDE + k0 + quad*8];
      acc[t] = __builtin_amdgcn_mfma_f32_16x16x32_f16(a, b, acc[t], 0, 0, 0);
    }
  }
}

template<int NT>
__device__ inline void epilogue(v4f* acc, half_t* outb, int rowbase, int colbase,
                                const float* bias, bool relu, int lane){
  int n = lane & 15, quad = lane >> 4;
#pragma unroll
  for (int t = 0; t < NT; t++){
    int col = colbase + t*16 + n;
    float bv = bias[col];
#pragma unroll
    for (int r = 0; r < 4; r++){
      float v = acc[t][r] + bv;
      if (relu) v = fmaxf(v, 0.f);
      outb[(rowbase + quad*4 + r)*ASTRIDE + col] = (half_t)v;
    }
  }
}

__global__ __launch_bounds__(256) void mlp_mfma(
    const float* qcw, const float* xyzdir, const half_t* wt,
    const float* b0, const float* b1, const float* b2, const float* b3,
    const float* bfb, const float* bdb,
    const float* Wsb, const float* bsb, const float* Wrb, const float* brb,
    float* out){
  __shared__ __align__(16) half_t Abuf[32*ASTRIDE];
  __shared__ __align__(16) half_t Pbuf[32*ASTRIDE];
  __shared__ __align__(16) half_t Qbuf[32*ASTRIDE];
  __shared__ __align__(16) half_t Dbuf[32*DSTRIDE];
  __shared__ __align__(16) half_t WL[128*ASTRIDE];

  int tid = threadIdx.x, lane = tid & 63, wave = tid >> 6;
  int qbase = blockIdx.x * 32;

  // stage input_xyz = [query_codes(64) | xyzdir[:,0:63] | 0]  (fp32 -> fp16)
  for (int i = tid; i < 32*ASTRIDE; i += 256){
    int r = i / ASTRIDE, c = i - r*ASTRIDE;
    size_t q = qbase + r;
    float v = 0.f;
    if (c < 64)       v = qcw[q*64 + c];
    else if (c < 127) v = xyzdir[q*90 + (c - 64)];
    Abuf[i] = (half_t)v;
  }
  // stage input_dir = xyzdir[:,63:90], zero-padded to 32
  for (int i = tid; i < 32*DSTRIDE; i += 256){
    int r = i / DSTRIDE, c = i - r*DSTRIDE;
    size_t q = qbase + r;
    float v = (c < 27) ? xyzdir[q*90 + 63 + c] : 0.f;
    Dbuf[i] = (half_t)v;
  }
  __syncthreads();

  int rowbase = (wave >> 1) * 16;
  int colbase = (wave & 1) * 64;
  v4f acc[4];

  const half_t* wt0 = wt;
  const half_t* wt1 = wt + 16384;
  const half_t* wt2 = wt + 32768;
  const half_t* wt3 = wt + 65536;
  const half_t* wtf = wt + 81920;
  const half_t* wtd = wt + 98304;

#define ZACC4() { for (int t_ = 0; t_ < 4; t_++) for (int e_ = 0; e_ < 4; e_++) acc[t_][e_] = 0.f; }

  // L0: A @ W0 -> P (relu)
  stage_w<128>(wt0, 128, 0, 128, WL, tid);
  __syncthreads();
  ZACC4();
  mfma_chunk<4>(Abuf, ASTRIDE, rowbase, colbase, WL, 128, acc, lane);
  epilogue<4>(acc, Pbuf, rowbase, colbase, b0, true, lane);
  __syncthreads();

  // L1: P @ W1 -> Q (relu)
  stage_w<128>(wt1, 128, 0, 128, WL, tid);
  __syncthreads();
  ZACC4();
  mfma_chunk<4>(Pbuf, ASTRIDE, rowbase, colbase, WL, 128, acc, lane);
  epilogue<4>(acc, Qbuf, rowbase, colbase, b1, true, lane);
  __syncthreads();

  // L2: [input_xyz | h1] @ W2 -> P (relu)   (K = 256, two chunks)
  stage_w<128>(wt2, 256, 0, 128, WL, tid);
  __syncthreads();
  ZACC4();
  mfma_chunk<4>(Abuf, ASTRIDE, rowbase, colbase, WL, 128, acc, lane);
  __syncthreads();
  stage_w<128>(wt2, 256, 128, 128, WL, tid);
  __syncthreads();
  mfma_chunk<4>(Qbuf, ASTRIDE, rowbase, colbase, WL, 128, acc, lane);
  epilogue<4>(acc, Pbuf, rowbase, colbase, b2, true, lane);
  __syncthreads();

  // L3: P @ W3 -> A (relu)   (A = h3, kept for sigma)
  stage_w<128>(wt3, 128, 0, 128, WL, tid);
  __syncthreads();
  ZACC4();
  mfma_chunk<4>(Pbuf, ASTRIDE, rowbase, colbase, WL, 128, acc, lane);
  epilogue<4>(acc, Abuf, rowbase, colbase, b3, true, lane);
  __syncthreads();

  // Wf: A(h3) @ Wf -> P (no relu)
  stage_w<128>(wtf, 128, 0, 128, WL, tid);
  __syncthreads();
  ZACC4();
  mfma_chunk<4>(Abuf, ASTRIDE, rowbase, colbase, WL, 128, acc, lane);
  epilogue<4>(acc, Pbuf, rowbase, colbase, bfb, false, lane);
  __syncthreads();

  // Wd: [P(final) | D(dir)] @ Wd -> Q[:,0:64] (relu), N = 64 -> NT = 2
  stage_w<128>(wtd, 160, 0, 64, WL, tid);
  __syncthreads();
  int colbase_d = (wave & 1) * 32;
  ZACC4();
  mfma_chunk<2>(Pbuf, ASTRIDE, rowbase, colbase_d, WL, 128, acc, lane);
  __syncthreads();
  stage_w<32>(wtd, 160, 128, 64, WL, tid);
  __syncthreads();
  mfma_chunk<2>(Dbuf, DSTRIDE, rowbase, colbase_d, WL, 32, acc, lane);
  epilogue<2>(acc, Qbuf, rowbase, colbase_d, bdb, true, lane);
  __syncthreads();

  // Tail: sigma = h3(Abuf) . Ws + bs ; rgb = d(Qbuf) . Wr + br
  {
    int q = tid >> 3, part = tid & 7;   // 8 threads per query
    float s = 0.f;
#pragma unroll
    for (int k = 0; k < 16; k++){
      int kk = part*16 + k;
      s = fmaf((float)Abuf[q*ASTRIDE + kk], Wsb[kk], s);
    }
    s += __shfl_xor(s, 1, 64); s += __shfl_xor(s, 2, 64); s += __shfl_xor(s, 4, 64);

    float r3[3];
#pragma unroll
    for (int c2 = 0; c2 < 3; c2++){
      float rv = 0.f;
#pragma unroll
      for (int k = 0; k < 8; k++){
        int kk = part*8 + k;
        rv = fmaf((float)Qbuf[q*ASTRIDE + kk], Wrb[kk*3 + c2], rv);
      }
      rv += __shfl_xor(rv, 1, 64); rv += __shfl_xor(rv, 2, 64); rv += __shfl_xor(rv, 4, 64);
      r3[c2] = rv;
    }
    if (part == 0){
      size_t ob = ((size_t)(qbase + q)) * 4;
      out[ob + 0] = r3[0] + brb[0];
      out[ob + 1] = r3[1] + brb[1];
      out[ob + 2] = r3[2] + brb[2];
      out[ob + 3] = s + bsb[0];
    }
  }
}

// ---------------------------------------------------------------------------
extern "C" void kernel_launch(void* const* d_in, const int* in_sizes, int n_in,
                              void* d_out, int out_size, void* d_ws, size_t ws_size,
                              hipStream_t stream){
  (void)in_sizes; (void)n_in; (void)out_size; (void)ws_size;

  const int*   indices = (const int*)d_in[0];
  const float* qpts    = (const float*)d_in[1];
  const float* xyzdir  = (const float*)d_in[2];
  const float* cpos    = (const float*)d_in[3];
  const float* codes   = (const float*)d_in[4];
  const float* W0 = (const float*)d_in[5];
  const float* b0 = (const float*)d_in[6];
  const float* W1 = (const float*)d_in[7];
  const float* b1 = (const float*)d_in[8];
  const float* W2 = (const float*)d_in[9];
  const float* b2 = (const float*)d_in[10];
  const float* W3 = (const float*)d_in[11];
  const float* b3 = (const float*)d_in[12];
  const float* Wf = (const float*)d_in[13];
  const float* bf = (const float*)d_in[14];
  const float* Wd = (const float*)d_in[15];
  const float* bd = (const float*)d_in[16];
  const float* Ws = (const float*)d_in[17];
  const float* bs = (const float*)d_in[18];
  const float* Wr = (const float*)d_in[19];
  const float* br = (const float*)d_in[20];

  float*  qcw = (float*)d_ws;                                  // 65536*64 fp32 = 16 MB
  half_t* wt  = (half_t*)((char*)d_ws + (size_t)N_Q*CDIM*4);   // 108544 fp16

  wtrans_kernel<<<(108544 + 255)/256, 256, 0, stream>>>(W0, W1, W2, W3, Wf, Wd, wt);
  knn_kernel<<<N_Q/64, 256, 0, stream>>>(indices, qpts, cpos, codes, qcw);
  mlp_mfma<<<N_Q/32, 256, 0, stream>>>(qcw, xyzdir, wt,
                                       b0, b1, b2, b3, bf, bd, Ws, bs, Wr, br,
                                       (float*)d_out);
}

// Round 5
// 352.102 us; speedup vs baseline: 9.5284x; 1.4419x over previous
//
#include <hip/hip_runtime.h>

#define N_Q   65536
#define N_C   2048
#define KNN_K 16
#define CDIM  64
#define SLCAP 256
#define KINF  0x7FFFFFFF

typedef _Float16 half_t;
typedef float v4f __attribute__((ext_vector_type(4)));
typedef half_t v8h __attribute__((ext_vector_type(8)));

#define ASTRIDE 136   // 128 + 8 pad (halves); row = 272 B = 17*16 B
#define DSTRIDE 40    // 32 + 8 pad

// ---------------------------------------------------------------------------
// Kernel 0: transpose/pad fp32 weights -> fp16 [n][k] layouts in ws.
// ---------------------------------------------------------------------------
__global__ void wtrans_kernel(const float* W0, const float* W1, const float* W2,
                              const float* W3, const float* Wf, const float* Wd,
                              half_t* wt){
  int idx = blockIdx.x * 256 + threadIdx.x;
  if (idx >= 108544) return;
  float val;
  if (idx < 16384){
    int i = idx, n = i >> 7, k = i & 127;
    val = (k < 127) ? W0[k*128 + n] : 0.f;
  } else if (idx < 32768){
    int i = idx - 16384, n = i >> 7, k = i & 127;
    val = W1[k*128 + n];
  } else if (idx < 65536){
    int i = idx - 32768, n = i >> 8, k = i & 255;
    val = (k == 127) ? 0.f : ((k < 127) ? W2[k*128 + n] : W2[(k-1)*128 + n]);
  } else if (idx < 81920){
    int i = idx - 65536, n = i >> 7, k = i & 127;
    val = W3[k*128 + n];
  } else if (idx < 98304){
    int i = idx - 81920, n = i >> 7, k = i & 127;
    val = Wf[k*128 + n];
  } else {
    int i = idx - 98304, n = i / 160, k = i - n*160;
    val = (k < 155) ? Wd[k*64 + n] : 0.f;
  }
  wt[idx] = (half_t)val;
}

// ---------------------------------------------------------------------------
// Kernel 1: exact 16-NN, tau-pruned. One WAVE per query (4 queries/block).
// Packed key: (d2_bits & ~0x7FF) | c -> min == argmin, ties -> lower index.
// tau = 16th-smallest lane-min (64-lane bitonic). #{keys<=tau} >= 16 always
// (16 smallest lane-mins are distinct candidates <= tau), and the global
// 16th-smallest key <= tau, so the filtered set contains the exact top-16.
// Fast path is exact whenever n in [16, SLCAP]; else exact fallback.
// ---------------------------------------------------------------------------
__global__ __launch_bounds__(256) void knn_kernel(const int* indices,
    const float* qpts, const float* cpos, const float* codes, float* qcw){
  __shared__ float lx[N_C], ly[N_C], lz[N_C];
  __shared__ int   sl[4*SLCAP];
  int tid = threadIdx.x;
  int lane = tid & 63, wave = tid >> 6;
  int idx0 = indices[0];
  const float* cp = cpos + (size_t)idx0 * N_C * 3;
  const float* cc = codes + (size_t)idx0 * N_C * CDIM;

  for (int c = tid; c < N_C; c += 256){
    lx[c] = cp[c*3 + 0];
    ly[c] = cp[c*3 + 1];
    lz[c] = cp[c*3 + 2];
  }
  __syncthreads();

  int q = blockIdx.x * 4 + wave;
  float qx = qpts[q*3 + 0];
  float qy = qpts[q*3 + 1];
  float qz = qpts[q*3 + 2];

  int p[32];
#pragma unroll
  for (int j = 0; j < 32; j++){
    int c = j*64 + lane;
    float dx = qx - lx[c], dy = qy - ly[c], dz = qz - lz[c];
    float d2 = fmaf(dz, dz, fmaf(dy, dy, dx*dx));
    p[j] = (__float_as_int(d2) & 0xFFFFF800) | c;
  }

  // lane-local min
  int lm = p[0];
#pragma unroll
  for (int j = 1; j < 32; j++) lm = min(lm, p[j]);

  // 64-lane bitonic sort of lane-mins (ascending by lane index)
  int v = lm;
#pragma unroll
  for (int k = 2; k <= 64; k <<= 1){
#pragma unroll
    for (int j = k >> 1; j > 0; j >>= 1){
      int o = __shfl_xor(v, j, 64);
      bool dirDesc = (lane & k) != 0;
      bool lower   = (lane & j) == 0;
      int mn = min(v, o), mx = max(v, o);
      v = ((lower != dirDesc)) ? mn : mx;
    }
  }
  int tau = __shfl(v, 15, 64);

  // filter count + prefix scan
  int cnt = 0;
#pragma unroll
  for (int j = 0; j < 32; j++) cnt += (p[j] <= tau) ? 1 : 0;
  int incl = cnt;
#pragma unroll
  for (int d = 1; d < 64; d <<= 1){
    int t = __shfl_up(incl, d, 64);
    incl += (lane >= d) ? t : 0;
  }
  int n = __shfl(incl, 63, 64);
  int base = incl - cnt;

  int keep = 0;
  if (n >= KNN_K && n <= SLCAP){
    // compact survivors into per-wave LDS list
    int* slw = &sl[wave * SLCAP];
    int off = base;
#pragma unroll
    for (int j = 0; j < 32; j++){
      if (p[j] <= tau){ slw[off] = p[j]; off++; }
    }
    __builtin_amdgcn_wave_barrier();

    int r[4];
#pragma unroll
    for (int i = 0; i < 4; i++){
      int idx = lane + (i << 6);
      r[i] = (idx < n) ? slw[idx] : KINF;
    }
#pragma unroll 1
    for (int rr = 0; rr < KNN_K; rr++){
      int t0 = min(r[0], r[1]), t1 = min(r[2], r[3]);
      int gm = min(t0, t1);
#pragma unroll
      for (int off2 = 1; off2 < 64; off2 <<= 1)
        gm = min(gm, __shfl_xor(gm, off2, 64));
      if (lane == rr) keep = gm;
#pragma unroll
      for (int i = 0; i < 4; i++) r[i] = (r[i] == gm) ? KINF : r[i];
    }
  } else {
    // exact fallback: full rescan extraction over p[32]
#pragma unroll 1
    for (int rr = 0; rr < KNN_K; rr++){
      int lmf = p[0];
#pragma unroll
      for (int j = 1; j < 32; j++) lmf = min(lmf, p[j]);
      int gm = lmf;
#pragma unroll
      for (int off2 = 1; off2 < 64; off2 <<= 1)
        gm = min(gm, __shfl_xor(gm, off2, 64));
      if (lane == rr) keep = gm;
#pragma unroll
      for (int j = 0; j < 32; j++) p[j] = (p[j] == gm) ? KINF : p[j];
    }
  }

  // exact d2 + inverse-d2 weights for lanes 0..15
  int ci = keep & 0x7FF;
  float dx = qx - lx[ci], dy = qy - ly[ci], dz = qz - lz[ci];
  float d2 = fmaf(dz, dz, fmaf(dy, dy, dx*dx));
  float w = 1.0f / (d2 + 1e-16f);
  float wm = (lane < KNN_K) ? w : 0.0f;
#pragma unroll
  for (int off2 = 1; off2 < 64; off2 <<= 1) wm += __shfl_xor(wm, off2, 64);
  float wn = w / wm;

  float acc = 0.f;
#pragma unroll
  for (int i = 0; i < KNN_K; i++){
    int   cb = __shfl(ci, i, 64);
    float wb = __shfl(wn, i, 64);
    acc = fmaf(wb, cc[cb*CDIM + lane], acc);
  }
  qcw[(size_t)q*CDIM + lane] = acc;
}

// ---------------------------------------------------------------------------
// Kernel 2: fused MFMA MLP. 32 queries/block, 256 threads (4 waves).
// ---------------------------------------------------------------------------
template<int KCH>
__device__ inline void stage_w(const half_t* wg, int Kstride, int k0, int Nout,
                               half_t* WLp, int tid){
  const int kd16 = KCH >> 3;         // 16B units per row
  int tot = Nout * kd16;
  for (int i = tid; i < tot; i += 256){
    int n = i / kd16, kk = i - n*kd16;
    *(uint4*)&WLp[n*ASTRIDE + (kk << 3)] =
        *(const uint4*)&wg[(size_t)n*Kstride + k0 + (kk << 3)];
  }
}

template<int NT>
__device__ inline void mfma_chunk(const half_t* act, int astride, int rowbase,
                                  int colbase, const half_t* WLp, int kchunk,
                                  v4f* acc, int lane){
  int m = lane & 15, quad = lane >> 4;
#pragma unroll 1
  for (int k0 = 0; k0 < kchunk; k0 += 32){
    v8h a = *(const v8h*)&act[(rowbase + m)*astride + k0 + quad*8];
#pragma unroll
    for (int t = 0; t < NT; t++){
      v8h b = *(const v8h*)&WLp[(colbase + t*16 + m)*ASTRIDE + k0 + quad*8];
      acc[t] = __builtin_amdgcn_mfma_f32_16x16x32_f16(a, b, acc[t], 0, 0, 0);
    }
  }
}

template<int NT>
__device__ inline void epilogue(v4f* acc, half_t* outb, int rowbase, int colbase,
                                const float* bias, bool relu, int lane){
  int n = lane & 15, quad = lane >> 4;
#pragma unroll
  for (int t = 0; t < NT; t++){
    int col = colbase + t*16 + n;
    float bv = bias[col];
#pragma unroll
    for (int r = 0; r < 4; r++){
      float v = acc[t][r] + bv;
      if (relu) v = fmaxf(v, 0.f);
      outb[(rowbase + quad*4 + r)*ASTRIDE + col] = (half_t)v;
    }
  }
}

__global__ __launch_bounds__(256) void mlp_mfma(
    const float* qcw, const float* xyzdir, const half_t* wt,
    const float* b0, const float* b1, const float* b2, const float* b3,
    const float* bfb, const float* bdb,
    const float* Wsb, const float* bsb, const float* Wrb, const float* brb,
    float* out){
  __shared__ __align__(16) half_t Abuf[32*ASTRIDE];
  __shared__ __align__(16) half_t Pbuf[32*ASTRIDE];
  __shared__ __align__(16) half_t Qbuf[32*ASTRIDE];
  __shared__ __align__(16) half_t Dbuf[32*DSTRIDE];
  __shared__ __align__(16) half_t WL[128*ASTRIDE];

  int tid = threadIdx.x, lane = tid & 63, wave = tid >> 6;
  int qbase = blockIdx.x * 32;

  for (int i = tid; i < 32*ASTRIDE; i += 256){
    int r = i / ASTRIDE, c = i - r*ASTRIDE;
    size_t q = qbase + r;
    float v = 0.f;
    if (c < 64)       v = qcw[q*64 + c];
    else if (c < 127) v = xyzdir[q*90 + (c - 64)];
    Abuf[i] = (half_t)v;
  }
  for (int i = tid; i < 32*DSTRIDE; i += 256){
    int r = i / DSTRIDE, c = i - r*DSTRIDE;
    size_t q = qbase + r;
    float v = (c < 27) ? xyzdir[q*90 + 63 + c] : 0.f;
    Dbuf[i] = (half_t)v;
  }
  __syncthreads();

  int rowbase = (wave >> 1) * 16;
  int colbase = (wave & 1) * 64;
  v4f acc[4];

  const half_t* wt0 = wt;
  const half_t* wt1 = wt + 16384;
  const half_t* wt2 = wt + 32768;
  const half_t* wt3 = wt + 65536;
  const half_t* wtf = wt + 81920;
  const half_t* wtd = wt + 98304;

#define ZACC4() { for (int t_ = 0; t_ < 4; t_++) for (int e_ = 0; e_ < 4; e_++) acc[t_][e_] = 0.f; }

  // L0
  stage_w<128>(wt0, 128, 0, 128, WL, tid);
  __syncthreads();
  ZACC4();
  mfma_chunk<4>(Abuf, ASTRIDE, rowbase, colbase, WL, 128, acc, lane);
  epilogue<4>(acc, Pbuf, rowbase, colbase, b0, true, lane);
  __syncthreads();

  // L1
  stage_w<128>(wt1, 128, 0, 128, WL, tid);
  __syncthreads();
  ZACC4();
  mfma_chunk<4>(Pbuf, ASTRIDE, rowbase, colbase, WL, 128, acc, lane);
  epilogue<4>(acc, Qbuf, rowbase, colbase, b1, true, lane);
  __syncthreads();

  // L2 (K = 256)
  stage_w<128>(wt2, 256, 0, 128, WL, tid);
  __syncthreads();
  ZACC4();
  mfma_chunk<4>(Abuf, ASTRIDE, rowbase, colbase, WL, 128, acc, lane);
  __syncthreads();
  stage_w<128>(wt2, 256, 128, 128, WL, tid);
  __syncthreads();
  mfma_chunk<4>(Qbuf, ASTRIDE, rowbase, colbase, WL, 128, acc, lane);
  epilogue<4>(acc, Pbuf, rowbase, colbase, b2, true, lane);
  __syncthreads();

  // L3 -> Abuf (h3 kept for sigma)
  stage_w<128>(wt3, 128, 0, 128, WL, tid);
  __syncthreads();
  ZACC4();
  mfma_chunk<4>(Pbuf, ASTRIDE, rowbase, colbase, WL, 128, acc, lane);
  epilogue<4>(acc, Abuf, rowbase, colbase, b3, true, lane);
  __syncthreads();

  // Wf
  stage_w<128>(wtf, 128, 0, 128, WL, tid);
  __syncthreads();
  ZACC4();
  mfma_chunk<4>(Abuf, ASTRIDE, rowbase, colbase, WL, 128, acc, lane);
  epilogue<4>(acc, Pbuf, rowbase, colbase, bfb, false, lane);
  __syncthreads();

  // Wd (N = 64)
  stage_w<128>(wtd, 160, 0, 64, WL, tid);
  __syncthreads();
  int colbase_d = (wave & 1) * 32;
  ZACC4();
  mfma_chunk<2>(Pbuf, ASTRIDE, rowbase, colbase_d, WL, 128, acc, lane);
  __syncthreads();
  stage_w<32>(wtd, 160, 128, 64, WL, tid);
  __syncthreads();
  mfma_chunk<2>(Dbuf, DSTRIDE, rowbase, colbase_d, WL, 32, acc, lane);
  epilogue<2>(acc, Qbuf, rowbase, colbase_d, bdb, true, lane);
  __syncthreads();

  // Tail: sigma = h3(Abuf).Ws + bs ; rgb = d(Qbuf).Wr + br
  {
    int q = tid >> 3, part = tid & 7;
    float s = 0.f;
#pragma unroll
    for (int k = 0; k < 16; k++){
      int kk = part*16 + k;
      s = fmaf((float)Abuf[q*ASTRIDE + kk], Wsb[kk], s);
    }
    s += __shfl_xor(s, 1, 64); s += __shfl_xor(s, 2, 64); s += __shfl_xor(s, 4, 64);

    float r3[3];
#pragma unroll
    for (int c2 = 0; c2 < 3; c2++){
      float rv = 0.f;
#pragma unroll
      for (int k = 0; k < 8; k++){
        int kk = part*8 + k;
        rv = fmaf((float)Qbuf[q*ASTRIDE + kk], Wrb[kk*3 + c2], rv);
      }
      rv += __shfl_xor(rv, 1, 64); rv += __shfl_xor(rv, 2, 64); rv += __shfl_xor(rv, 4, 64);
      r3[c2] = rv;
    }
    if (part == 0){
      size_t ob = ((size_t)(qbase + q)) * 4;
      out[ob + 0] = r3[0] + brb[0];
      out[ob + 1] = r3[1] + brb[1];
      out[ob + 2] = r3[2] + brb[2];
      out[ob + 3] = s + bsb[0];
    }
  }
}

// ---------------------------------------------------------------------------
extern "C" void kernel_launch(void* const* d_in, const int* in_sizes, int n_in,
                              void* d_out, int out_size, void* d_ws, size_t ws_size,
                              hipStream_t stream){
  (void)in_sizes; (void)n_in; (void)out_size; (void)ws_size;

  const int*   indices = (const int*)d_in[0];
  const float* qpts    = (const float*)d_in[1];
  const float* xyzdir  = (const float*)d_in[2];
  const float* cpos    = (const float*)d_in[3];
  const float* codes   = (const float*)d_in[4];
  const float* W0 = (const float*)d_in[5];
  const float* b0 = (const float*)d_in[6];
  const float* W1 = (const float*)d_in[7];
  const float* b1 = (const float*)d_in[8];
  const float* W2 = (const float*)d_in[9];
  const float* b2 = (const float*)d_in[10];
  const float* W3 = (const float*)d_in[11];
  const float* b3 = (const float*)d_in[12];
  const float* Wf = (const float*)d_in[13];
  const float* bf = (const float*)d_in[14];
  const float* Wd = (const float*)d_in[15];
  const float* bd = (const float*)d_in[16];
  const float* Ws = (const float*)d_in[17];
  const float* bs = (const float*)d_in[18];
  const float* Wr = (const float*)d_in[19];
  const float* br = (const float*)d_in[20];

  float*  qcw = (float*)d_ws;                                  // 16 MB
  half_t* wt  = (half_t*)((char*)d_ws + (size_t)N_Q*CDIM*4);   // 108544 fp16

  wtrans_kernel<<<(108544 + 255)/256, 256, 0, stream>>>(W0, W1, W2, W3, Wf, Wd, wt);
  knn_kernel<<<N_Q/4, 256, 0, stream>>>(indices, qpts, cpos, codes, qcw);
  mlp_mfma<<<N_Q/32, 256, 0, stream>>>(qcw, xyzdir, wt,
                                       b0, b1, b2, b3, bf, bd, Ws, bs, Wr, br,
                                       (float*)d_out);
}

// Round 6
// 341.476 us; speedup vs baseline: 9.8249x; 1.0311x over previous
//
#include <hip/hip_runtime.h>

#define N_Q   65536
#define N_C   2048
#define KNN_K 16
#define CDIM  64
#define SLCAP 256
#define KINF  0x7FFFFFFF

typedef _Float16 half_t;
typedef float v4f __attribute__((ext_vector_type(4)));
typedef half_t v8h __attribute__((ext_vector_type(8)));

#define ASTRIDE 136   // 128 + 8 pad (halves); row = 272 B = 17*16 B
#define DSTRIDE 40    // 32 + 8 pad

// ---------------------------------------------------------------------------
// Kernel 0: transpose/pad fp32 weights -> fp16 [n][k] layouts in ws.
//  wt0 : 128n x 128k  (k==127 -> 0)                       @ 0
//  wt1 : 128n x 128k                                      @ 16384
//  wt2 : 128n x 256k  (k==127 -> 0, k>=128 -> W2[k-1])    @ 32768
//  wt3 : 128n x 128k                                      @ 65536
//  wtf : 128n x 128k                                      @ 81920
//  wtd :  64n x 160k  (k>=155 -> 0)                       @ 98304
// ---------------------------------------------------------------------------
__global__ void wtrans_kernel(const float* W0, const float* W1, const float* W2,
                              const float* W3, const float* Wf, const float* Wd,
                              half_t* wt){
  int idx = blockIdx.x * 256 + threadIdx.x;
  if (idx >= 108544) return;
  float val;
  if (idx < 16384){
    int i = idx, n = i >> 7, k = i & 127;
    val = (k < 127) ? W0[k*128 + n] : 0.f;
  } else if (idx < 32768){
    int i = idx - 16384, n = i >> 7, k = i & 127;
    val = W1[k*128 + n];
  } else if (idx < 65536){
    int i = idx - 32768, n = i >> 8, k = i & 255;
    val = (k == 127) ? 0.f : ((k < 127) ? W2[k*128 + n] : W2[(k-1)*128 + n]);
  } else if (idx < 81920){
    int i = idx - 65536, n = i >> 7, k = i & 127;
    val = W3[k*128 + n];
  } else if (idx < 98304){
    int i = idx - 81920, n = i >> 7, k = i & 127;
    val = Wf[k*128 + n];
  } else {
    int i = idx - 98304, n = i / 160, k = i - n*160;
    val = (k < 155) ? Wd[k*64 + n] : 0.f;
  }
  wt[idx] = (half_t)val;
}

// ---------------------------------------------------------------------------
// Kernel 1: exact 16-NN, tau-pruned + single bitonic selection.
// One WAVE per query (4/block). Key: (d2_bits & ~0x7FF) | c.
// tau = 16th-smallest lane-min. n = #{keys<=tau}. n>=16 <=> kappa<=tau
// => survivors contain the exact top-16 (checked at runtime; the tau-sort
// itself needs no trust). Fast path (n<=64): one 64-lane bitonic sort of
// survivors -> lanes 0..15 hold top-16. Middle (n<=256): r[4] extraction.
// Else: full exact fallback.
// ---------------------------------------------------------------------------
__global__ __launch_bounds__(256) void knn_kernel(const int* indices,
    const float* qpts, const float* cpos, const float* codes, float* qcw){
  __shared__ float4 lp[N_C];       // 32 KB
  __shared__ int    sl[4*SLCAP];   // 4 KB
  int tid = threadIdx.x;
  int lane = tid & 63, wave = tid >> 6;
  int idx0 = indices[0];
  const float* cp = cpos + (size_t)idx0 * N_C * 3;
  const float* cc = codes + (size_t)idx0 * N_C * CDIM;

  for (int c = tid; c < N_C; c += 256){
    lp[c] = make_float4(cp[c*3 + 0], cp[c*3 + 1], cp[c*3 + 2], 0.f);
  }
  __syncthreads();

  int q = blockIdx.x * 4 + wave;
  float qx = qpts[q*3 + 0];
  float qy = qpts[q*3 + 1];
  float qz = qpts[q*3 + 2];

  int p[32];
#pragma unroll
  for (int j = 0; j < 32; j++){
    int c = j*64 + lane;
    float4 P = lp[c];
    float dx = qx - P.x, dy = qy - P.y, dz = qz - P.z;
    float d2 = fmaf(dz, dz, fmaf(dy, dy, dx*dx));
    p[j] = (__float_as_int(d2) & 0xFFFFF800) | c;
  }

  // lane-local min
  int lm = p[0];
#pragma unroll
  for (int j = 1; j < 32; j++) lm = min(lm, p[j]);

  // 64-lane bitonic sort of lane-mins -> tau = 16th smallest
  int v = lm;
#pragma unroll
  for (int k = 2; k <= 64; k <<= 1){
#pragma unroll
    for (int j = k >> 1; j > 0; j >>= 1){
      int o = __shfl_xor(v, j, 64);
      bool dirDesc = (lane & k) != 0;
      bool lower   = (lane & j) == 0;
      int mn = min(v, o), mx = max(v, o);
      v = (lower != dirDesc) ? mn : mx;
    }
  }
  int tau = __shfl(v, 15, 64);

  // filter count + prefix scan
  int cnt = 0;
#pragma unroll
  for (int j = 0; j < 32; j++) cnt += (p[j] <= tau) ? 1 : 0;
  int incl = cnt;
#pragma unroll
  for (int d = 1; d < 64; d <<= 1){
    int t = __shfl_up(incl, d, 64);
    incl += (lane >= d) ? t : 0;
  }
  int n = __shfl(incl, 63, 64);
  int base = incl - cnt;

  int keep = 0;
  if (n >= KNN_K && n <= SLCAP){
    // compact survivors into per-wave LDS list
    int* slw = &sl[wave * SLCAP];
    int off = base;
#pragma unroll
    for (int j = 0; j < 32; j++){
      if (p[j] <= tau){ slw[off] = p[j]; off++; }
    }
    __builtin_amdgcn_wave_barrier();

    if (n <= 64){
      // one survivor per lane; full bitonic sort -> lane i = i-th smallest
      int x = (lane < n) ? slw[lane] : KINF;
#pragma unroll
      for (int k = 2; k <= 64; k <<= 1){
#pragma unroll
        for (int j = k >> 1; j > 0; j >>= 1){
          int o = __shfl_xor(x, j, 64);
          bool dirDesc = (lane & k) != 0;
          bool lower   = (lane & j) == 0;
          int mn = min(x, o), mx = max(x, o);
          x = (lower != dirDesc) ? mn : mx;
        }
      }
      keep = x;
    } else {
      int r[4];
#pragma unroll
      for (int i = 0; i < 4; i++){
        int idx = lane + (i << 6);
        r[i] = (idx < n) ? slw[idx] : KINF;
      }
#pragma unroll 1
      for (int rr = 0; rr < KNN_K; rr++){
        int t0 = min(r[0], r[1]), t1 = min(r[2], r[3]);
        int gm = min(t0, t1);
#pragma unroll
        for (int off2 = 1; off2 < 64; off2 <<= 1)
          gm = min(gm, __shfl_xor(gm, off2, 64));
        if (lane == rr) keep = gm;
#pragma unroll
        for (int i = 0; i < 4; i++) r[i] = (r[i] == gm) ? KINF : r[i];
      }
    }
  } else {
    // exact fallback: full rescan extraction over p[32]
#pragma unroll 1
    for (int rr = 0; rr < KNN_K; rr++){
      int lmf = p[0];
#pragma unroll
      for (int j = 1; j < 32; j++) lmf = min(lmf, p[j]);
      int gm = lmf;
#pragma unroll
      for (int off2 = 1; off2 < 64; off2 <<= 1)
        gm = min(gm, __shfl_xor(gm, off2, 64));
      if (lane == rr) keep = gm;
#pragma unroll
      for (int j = 0; j < 32; j++) p[j] = (p[j] == gm) ? KINF : p[j];
    }
  }

  // exact d2 + inverse-d2 weights for lanes 0..15
  int ci = keep & 0x7FF;
  float4 P = lp[ci];
  float dx = qx - P.x, dy = qy - P.y, dz = qz - P.z;
  float d2 = fmaf(dz, dz, fmaf(dy, dy, dx*dx));
  float w = 1.0f / (d2 + 1e-16f);
  float wm = (lane < KNN_K) ? w : 0.0f;
#pragma unroll
  for (int off2 = 1; off2 < 64; off2 <<= 1) wm += __shfl_xor(wm, off2, 64);
  float wn = w / wm;

  float acc = 0.f;
#pragma unroll
  for (int i = 0; i < KNN_K; i++){
    int   cb = __shfl(ci, i, 64);
    float wb = __shfl(wn, i, 64);
    acc = fmaf(wb, cc[cb*CDIM + lane], acc);
  }
  qcw[(size_t)q*CDIM + lane] = acc;
}

// ---------------------------------------------------------------------------
// Kernel 2: fused MFMA MLP, B-fragments direct from global (weights are
// L2-resident: 217 KB total). 32 queries/block, 256 threads (4 waves).
// LDS = 28.7 KB -> 5 blocks/CU. Syncs: 8 (activation ping-pong only).
// ---------------------------------------------------------------------------
template<int NT>
__device__ inline void mfma_gb(const half_t* act, int astride, int rowbase,
                               const half_t* wg, int Kstride, int k0base,
                               int colbase, int kchunk, v4f* acc, int lane){
  int m = lane & 15, quad = lane >> 4;
#pragma unroll
  for (int k0 = 0; k0 < kchunk; k0 += 32){
    v8h a = *(const v8h*)&act[(rowbase + m)*astride + k0 + quad*8];
#pragma unroll
    for (int t = 0; t < NT; t++){
      const half_t* bp = wg + (size_t)(colbase + t*16 + m)*Kstride
                            + k0base + k0 + quad*8;
      v8h b = *(const v8h*)bp;
      acc[t] = __builtin_amdgcn_mfma_f32_16x16x32_f16(a, b, acc[t], 0, 0, 0);
    }
  }
}

template<int NT>
__device__ inline void epilogue(v4f* acc, half_t* outb, int rowbase, int colbase,
                                const float* bias, bool relu, int lane){
  int n = lane & 15, quad = lane >> 4;
#pragma unroll
  for (int t = 0; t < NT; t++){
    int col = colbase + t*16 + n;
    float bv = bias[col];
#pragma unroll
    for (int r = 0; r < 4; r++){
      float v = acc[t][r] + bv;
      if (relu) v = fmaxf(v, 0.f);
      outb[(rowbase + quad*4 + r)*ASTRIDE + col] = (half_t)v;
    }
  }
}

__global__ __launch_bounds__(256) void mlp_mfma(
    const float* qcw, const float* xyzdir, const half_t* wt,
    const float* b0, const float* b1, const float* b2, const float* b3,
    const float* bfb, const float* bdb,
    const float* Wsb, const float* bsb, const float* Wrb, const float* brb,
    float* out){
  __shared__ __align__(16) half_t Abuf[32*ASTRIDE];
  __shared__ __align__(16) half_t Pbuf[32*ASTRIDE];
  __shared__ __align__(16) half_t Qbuf[32*ASTRIDE];
  __shared__ __align__(16) half_t Dbuf[32*DSTRIDE];

  int tid = threadIdx.x, lane = tid & 63, wave = tid >> 6;
  int qbase = blockIdx.x * 32;

  for (int i = tid; i < 32*ASTRIDE; i += 256){
    int r = i / ASTRIDE, c = i - r*ASTRIDE;
    size_t q = qbase + r;
    float v = 0.f;
    if (c < 64)       v = qcw[q*64 + c];
    else if (c < 127) v = xyzdir[q*90 + (c - 64)];
    Abuf[i] = (half_t)v;
  }
  for (int i = tid; i < 32*DSTRIDE; i += 256){
    int r = i / DSTRIDE, c = i - r*DSTRIDE;
    size_t q = qbase + r;
    float v = (c < 27) ? xyzdir[q*90 + 63 + c] : 0.f;
    Dbuf[i] = (half_t)v;
  }
  __syncthreads();

  int rowbase = (wave >> 1) * 16;
  int colbase = (wave & 1) * 64;
  v4f acc[4];

  const half_t* wt0 = wt;
  const half_t* wt1 = wt + 16384;
  const half_t* wt2 = wt + 32768;
  const half_t* wt3 = wt + 65536;
  const half_t* wtf = wt + 81920;
  const half_t* wtd = wt + 98304;

#define ZACC4() { for (int t_ = 0; t_ < 4; t_++) for (int e_ = 0; e_ < 4; e_++) acc[t_][e_] = 0.f; }

  // L0: A @ W0 -> P (relu)
  ZACC4();
  mfma_gb<4>(Abuf, ASTRIDE, rowbase, wt0, 128, 0, colbase, 128, acc, lane);
  epilogue<4>(acc, Pbuf, rowbase, colbase, b0, true, lane);
  __syncthreads();

  // L1: P @ W1 -> Q (relu)
  ZACC4();
  mfma_gb<4>(Pbuf, ASTRIDE, rowbase, wt1, 128, 0, colbase, 128, acc, lane);
  epilogue<4>(acc, Qbuf, rowbase, colbase, b1, true, lane);
  __syncthreads();

  // L2: [input_xyz | h1] @ W2 -> P (relu)   (K = 256)
  ZACC4();
  mfma_gb<4>(Abuf, ASTRIDE, rowbase, wt2, 256, 0,   colbase, 128, acc, lane);
  mfma_gb<4>(Qbuf, ASTRIDE, rowbase, wt2, 256, 128, colbase, 128, acc, lane);
  epilogue<4>(acc, Pbuf, rowbase, colbase, b2, true, lane);
  __syncthreads();

  // L3: P @ W3 -> A (h3, kept for sigma; input_xyz dead after L2)
  ZACC4();
  mfma_gb<4>(Pbuf, ASTRIDE, rowbase, wt3, 128, 0, colbase, 128, acc, lane);
  epilogue<4>(acc, Abuf, rowbase, colbase, b3, true, lane);
  __syncthreads();

  // Wf: A(h3) @ Wf -> P (no relu)
  ZACC4();
  mfma_gb<4>(Abuf, ASTRIDE, rowbase, wtf, 128, 0, colbase, 128, acc, lane);
  epilogue<4>(acc, Pbuf, rowbase, colbase, bfb, false, lane);
  __syncthreads();

  // Wd: [P(final) | D(dir)] @ Wd -> Q[:,0:64] (relu), N = 64
  int colbase_d = (wave & 1) * 32;
  ZACC4();
  mfma_gb<2>(Pbuf, ASTRIDE, rowbase, wtd, 160, 0,   colbase_d, 128, acc, lane);
  mfma_gb<2>(Dbuf, DSTRIDE, rowbase, wtd, 160, 128, colbase_d,  32, acc, lane);
  epilogue<2>(acc, Qbuf, rowbase, colbase_d, bdb, true, lane);
  __syncthreads();

  // Tail: sigma = h3(Abuf).Ws + bs ; rgb = d(Qbuf).Wr + br
  {
    int q = tid >> 3, part = tid & 7;
    float s = 0.f;
#pragma unroll
    for (int k = 0; k < 16; k++){
      int kk = part*16 + k;
      s = fmaf((float)Abuf[q*ASTRIDE + kk], Wsb[kk], s);
    }
    s += __shfl_xor(s, 1, 64); s += __shfl_xor(s, 2, 64); s += __shfl_xor(s, 4, 64);

    float r3[3];
#pragma unroll
    for (int c2 = 0; c2 < 3; c2++){
      float rv = 0.f;
#pragma unroll
      for (int k = 0; k < 8; k++){
        int kk = part*8 + k;
        rv = fmaf((float)Qbuf[q*ASTRIDE + kk], Wrb[kk*3 + c2], rv);
      }
      rv += __shfl_xor(rv, 1, 64); rv += __shfl_xor(rv, 2, 64); rv += __shfl_xor(rv, 4, 64);
      r3[c2] = rv;
    }
    if (part == 0){
      size_t ob = ((size_t)(qbase + q)) * 4;
      out[ob + 0] = r3[0] + brb[0];
      out[ob + 1] = r3[1] + brb[1];
      out[ob + 2] = r3[2] + brb[2];
      out[ob + 3] = s + bsb[0];
    }
  }
}

// ---------------------------------------------------------------------------
extern "C" void kernel_launch(void* const* d_in, const int* in_sizes, int n_in,
                              void* d_out, int out_size, void* d_ws, size_t ws_size,
                              hipStream_t stream){
  (void)in_sizes; (void)n_in; (void)out_size; (void)ws_size;

  const int*   indices = (const int*)d_in[0];
  const float* qpts    = (const float*)d_in[1];
  const float* xyzdir  = (const float*)d_in[2];
  const float* cpos    = (const float*)d_in[3];
  const float* codes   = (const float*)d_in[4];
  const float* W0 = (const float*)d_in[5];
  const float* b0 = (const float*)d_in[6];
  const float* W1 = (const float*)d_in[7];
  const float* b1 = (const float*)d_in[8];
  const float* W2 = (const float*)d_in[9];
  const float* b2 = (const float*)d_in[10];
  const float* W3 = (const float*)d_in[11];
  const float* b3 = (const float*)d_in[12];
  const float* Wf = (const float*)d_in[13];
  const float* bf = (const float*)d_in[14];
  const float* Wd = (const float*)d_in[15];
  const float* bd = (const float*)d_in[16];
  const float* Ws = (const float*)d_in[17];
  const float* bs = (const float*)d_in[18];
  const float* Wr = (const float*)d_in[19];
  const float* br = (const float*)d_in[20];

  float*  qcw = (float*)d_ws;                                  // 16 MB
  half_t* wt  = (half_t*)((char*)d_ws + (size_t)N_Q*CDIM*4);   // 108544 fp16

  wtrans_kernel<<<(108544 + 255)/256, 256, 0, stream>>>(W0, W1, W2, W3, Wf, Wd, wt);
  knn_kernel<<<N_Q/4, 256, 0, stream>>>(indices, qpts, cpos, codes, qcw);
  mlp_mfma<<<N_Q/32, 256, 0, stream>>>(qcw, xyzdir, wt,
                                       b0, b1, b2, b3, bf, bd, Ws, bs, Wr, br,
                                       (float*)d_out);
}

// Round 7
// 307.370 us; speedup vs baseline: 10.9151x; 1.1110x over previous
//
#include <hip/hip_runtime.h>

#define N_Q   65536
#define N_C   2048
#define KNN_K 16
#define CDIM  64
#define SLCAP 64
#define KINF  0x7FFFFFFF

typedef _Float16 half_t;
typedef float v4f __attribute__((ext_vector_type(4)));
typedef half_t v8h __attribute__((ext_vector_type(8)));

#define ASTRIDE 136   // 128 + 8 pad (halves); row = 272 B = 17*16 B
#define DSTRIDE 40    // 32 + 8 pad

// ---------------------------------------------------------------------------
// Kernel 0: transpose/pad fp32 weights -> fp16 [n][k] layouts in ws, plus
// cpos4[c] = (x, y, z, |c|^2 + 4) for the KNN score trick.
//  wt0 : 128n x 128k  (k==127 -> 0)                       @ 0
//  wt1 : 128n x 128k                                      @ 16384
//  wt2 : 128n x 256k  (k==127 -> 0, k>=128 -> W2[k-1])    @ 32768
//  wt3 : 128n x 128k                                      @ 65536
//  wtf : 128n x 128k                                      @ 81920
//  wtd :  64n x 160k  (k>=155 -> 0)                       @ 98304
// ---------------------------------------------------------------------------
__global__ void wtrans_kernel(const float* W0, const float* W1, const float* W2,
                              const float* W3, const float* Wf, const float* Wd,
                              const int* indices, const float* cpos,
                              half_t* wt, float4* cpos4){
  int idx = blockIdx.x * 256 + threadIdx.x;
  if (idx >= 110592) return;
  if (idx >= 108544){
    int i = idx - 108544;
    const float* cp = cpos + (size_t)indices[0] * N_C * 3;
    float x = cp[i*3 + 0], y = cp[i*3 + 1], z = cp[i*3 + 2];
    cpos4[i] = make_float4(x, y, z, fmaf(x, x, fmaf(y, y, fmaf(z, z, 4.0f))));
    return;
  }
  float val;
  if (idx < 16384){
    int i = idx, n = i >> 7, k = i & 127;
    val = (k < 127) ? W0[k*128 + n] : 0.f;
  } else if (idx < 32768){
    int i = idx - 16384, n = i >> 7, k = i & 127;
    val = W1[k*128 + n];
  } else if (idx < 65536){
    int i = idx - 32768, n = i >> 8, k = i & 255;
    val = (k == 127) ? 0.f : ((k < 127) ? W2[k*128 + n] : W2[(k-1)*128 + n]);
  } else if (idx < 81920){
    int i = idx - 65536, n = i >> 7, k = i & 127;
    val = W3[k*128 + n];
  } else if (idx < 98304){
    int i = idx - 81920, n = i >> 7, k = i & 127;
    val = Wf[k*128 + n];
  } else {
    int i = idx - 98304, n = i / 160, k = i - n*160;
    val = (k < 155) ? Wd[k*64 + n] : 0.f;
  }
  wt[idx] = (half_t)val;
}

// ---------------------------------------------------------------------------
// Kernel 1: exact 16-NN, tau-pruned. One WAVE per query, 8 queries/block
// (512 thr). Score = |c|^2+4 - 2 q.c (3 FMAs, monotone-with-d2 up to fp32
// rounding; reference uses the same expansion). Key = (score_bits & ~0x7FF)|c.
// tau = 16th-smallest lane-min; n = #{key<=tau}; n>=16 <=> survivors contain
// the exact top-16 (runtime-checked). Fast path n<=64: one 64-lane bitonic
// sort -> lanes 0..15 = top-16. Else: exact full-rescan fallback.
// Weights use exact recomputed d2, so selection noise only swaps near-ties.
// ---------------------------------------------------------------------------
__global__ __launch_bounds__(512, 8) void knn_kernel(const int* indices,
    const float* qpts, const float4* cpos4, const float* codes, float* qcw){
  __shared__ float4 lp[N_C];        // 32 KB
  __shared__ int    sl[8*SLCAP];    // 2 KB
  int tid = threadIdx.x;
  int lane = tid & 63, wave = tid >> 6;
  const float* cc = codes + (size_t)indices[0] * N_C * CDIM;

  for (int c = tid; c < N_C; c += 512) lp[c] = cpos4[c];
  __syncthreads();

  int q = blockIdx.x * 8 + wave;
  float qx = qpts[q*3 + 0];
  float qy = qpts[q*3 + 1];
  float qz = qpts[q*3 + 2];
  float nqx = -2.0f*qx, nqy = -2.0f*qy, nqz = -2.0f*qz;

  int p[32];
#pragma unroll
  for (int j = 0; j < 32; j++){
    int c = j*64 + lane;
    float4 P = lp[c];
    float s = fmaf(P.x, nqx, fmaf(P.y, nqy, fmaf(P.z, nqz, P.w)));  // > 0
    p[j] = (__float_as_int(s) & 0xFFFFF800) | c;
  }

  // lane-local min
  int lm = p[0];
#pragma unroll
  for (int j = 1; j < 32; j++) lm = min(lm, p[j]);

  // 64-lane bitonic sort of lane-mins -> tau = 16th smallest
  int v = lm;
#pragma unroll
  for (int k = 2; k <= 64; k <<= 1){
#pragma unroll
    for (int j = k >> 1; j > 0; j >>= 1){
      int o = __shfl_xor(v, j, 64);
      bool dirDesc = (lane & k) != 0;
      bool lower   = (lane & j) == 0;
      int mn = min(v, o), mx = max(v, o);
      v = (lower != dirDesc) ? mn : mx;
    }
  }
  int tau = __shfl(v, 15, 64);

  // filter count + prefix scan
  int cnt = 0;
#pragma unroll
  for (int j = 0; j < 32; j++) cnt += (p[j] <= tau) ? 1 : 0;
  int incl = cnt;
#pragma unroll
  for (int d = 1; d < 64; d <<= 1){
    int t = __shfl_up(incl, d, 64);
    incl += (lane >= d) ? t : 0;
  }
  int n = __shfl(incl, 63, 64);
  int base = incl - cnt;

  int keep = 0;
  if (n >= KNN_K && n <= SLCAP){
    int* slw = &sl[wave * SLCAP];
    int off = base;
#pragma unroll
    for (int j = 0; j < 32; j++){
      if (p[j] <= tau){ slw[off] = p[j]; off++; }
    }
    __builtin_amdgcn_wave_barrier();

    int x = (lane < n) ? slw[lane] : KINF;
#pragma unroll
    for (int k = 2; k <= 64; k <<= 1){
#pragma unroll
      for (int j = k >> 1; j > 0; j >>= 1){
        int o = __shfl_xor(x, j, 64);
        bool dirDesc = (lane & k) != 0;
        bool lower   = (lane & j) == 0;
        int mn = min(x, o), mx = max(x, o);
        x = (lower != dirDesc) ? mn : mx;
      }
    }
    keep = x;
  } else {
    // exact fallback: full rescan extraction over p[32] (rare)
#pragma unroll 1
    for (int rr = 0; rr < KNN_K; rr++){
      int lmf = p[0];
#pragma unroll
      for (int j = 1; j < 32; j++) lmf = min(lmf, p[j]);
      int gm = lmf;
#pragma unroll
      for (int off2 = 1; off2 < 64; off2 <<= 1)
        gm = min(gm, __shfl_xor(gm, off2, 64));
      if (lane == rr) keep = gm;
#pragma unroll
      for (int j = 0; j < 32; j++) p[j] = (p[j] == gm) ? KINF : p[j];
    }
  }

  // exact d2 + inverse-d2 weights for lanes 0..15
  int ci = keep & 0x7FF;
  float4 P = lp[ci];
  float dx = qx - P.x, dy = qy - P.y, dz = qz - P.z;
  float d2 = fmaf(dz, dz, fmaf(dy, dy, dx*dx));
  float w = 1.0f / (d2 + 1e-16f);
  float wm = (lane < KNN_K) ? w : 0.0f;
#pragma unroll
  for (int off2 = 1; off2 < 64; off2 <<= 1) wm += __shfl_xor(wm, off2, 64);
  float wn = w / wm;

  float acc = 0.f;
#pragma unroll
  for (int i = 0; i < KNN_K; i++){
    int   cb = __shfl(ci, i, 64);
    float wb = __shfl(wn, i, 64);
    acc = fmaf(wb, cc[cb*CDIM + lane], acc);
  }
  qcw[(size_t)q*CDIM + lane] = acc;
}

// ---------------------------------------------------------------------------
// Kernel 2: fused MFMA MLP, B-fragments direct from global (weights are
// L2-resident: 217 KB total). 32 queries/block, 256 threads (4 waves).
// UNCHANGED from round 6 (frozen to isolate the KNN change).
// ---------------------------------------------------------------------------
template<int NT>
__device__ inline void mfma_gb(const half_t* act, int astride, int rowbase,
                               const half_t* wg, int Kstride, int k0base,
                               int colbase, int kchunk, v4f* acc, int lane){
  int m = lane & 15, quad = lane >> 4;
#pragma unroll
  for (int k0 = 0; k0 < kchunk; k0 += 32){
    v8h a = *(const v8h*)&act[(rowbase + m)*astride + k0 + quad*8];
#pragma unroll
    for (int t = 0; t < NT; t++){
      const half_t* bp = wg + (size_t)(colbase + t*16 + m)*Kstride
                            + k0base + k0 + quad*8;
      v8h b = *(const v8h*)bp;
      acc[t] = __builtin_amdgcn_mfma_f32_16x16x32_f16(a, b, acc[t], 0, 0, 0);
    }
  }
}

template<int NT>
__device__ inline void epilogue(v4f* acc, half_t* outb, int rowbase, int colbase,
                                const float* bias, bool relu, int lane){
  int n = lane & 15, quad = lane >> 4;
#pragma unroll
  for (int t = 0; t < NT; t++){
    int col = colbase + t*16 + n;
    float bv = bias[col];
#pragma unroll
    for (int r = 0; r < 4; r++){
      float v = acc[t][r] + bv;
      if (relu) v = fmaxf(v, 0.f);
      outb[(rowbase + quad*4 + r)*ASTRIDE + col] = (half_t)v;
    }
  }
}

__global__ __launch_bounds__(256) void mlp_mfma(
    const float* qcw, const float* xyzdir, const half_t* wt,
    const float* b0, const float* b1, const float* b2, const float* b3,
    const float* bfb, const float* bdb,
    const float* Wsb, const float* bsb, const float* Wrb, const float* brb,
    float* out){
  __shared__ __align__(16) half_t Abuf[32*ASTRIDE];
  __shared__ __align__(16) half_t Pbuf[32*ASTRIDE];
  __shared__ __align__(16) half_t Qbuf[32*ASTRIDE];
  __shared__ __align__(16) half_t Dbuf[32*DSTRIDE];

  int tid = threadIdx.x, lane = tid & 63, wave = tid >> 6;
  int qbase = blockIdx.x * 32;

  for (int i = tid; i < 32*ASTRIDE; i += 256){
    int r = i / ASTRIDE, c = i - r*ASTRIDE;
    size_t q = qbase + r;
    float v = 0.f;
    if (c < 64)       v = qcw[q*64 + c];
    else if (c < 127) v = xyzdir[q*90 + (c - 64)];
    Abuf[i] = (half_t)v;
  }
  for (int i = tid; i < 32*DSTRIDE; i += 256){
    int r = i / DSTRIDE, c = i - r*DSTRIDE;
    size_t q = qbase + r;
    float v = (c < 27) ? xyzdir[q*90 + 63 + c] : 0.f;
    Dbuf[i] = (half_t)v;
  }
  __syncthreads();

  int rowbase = (wave >> 1) * 16;
  int colbase = (wave & 1) * 64;
  v4f acc[4];

  const half_t* wt0 = wt;
  const half_t* wt1 = wt + 16384;
  const half_t* wt2 = wt + 32768;
  const half_t* wt3 = wt + 65536;
  const half_t* wtf = wt + 81920;
  const half_t* wtd = wt + 98304;

#define ZACC4() { for (int t_ = 0; t_ < 4; t_++) for (int e_ = 0; e_ < 4; e_++) acc[t_][e_] = 0.f; }

  // L0: A @ W0 -> P (relu)
  ZACC4();
  mfma_gb<4>(Abuf, ASTRIDE, rowbase, wt0, 128, 0, colbase, 128, acc, lane);
  epilogue<4>(acc, Pbuf, rowbase, colbase, b0, true, lane);
  __syncthreads();

  // L1: P @ W1 -> Q (relu)
  ZACC4();
  mfma_gb<4>(Pbuf, ASTRIDE, rowbase, wt1, 128, 0, colbase, 128, acc, lane);
  epilogue<4>(acc, Qbuf, rowbase, colbase, b1, true, lane);
  __syncthreads();

  // L2: [input_xyz | h1] @ W2 -> P (relu)   (K = 256)
  ZACC4();
  mfma_gb<4>(Abuf, ASTRIDE, rowbase, wt2, 256, 0,   colbase, 128, acc, lane);
  mfma_gb<4>(Qbuf, ASTRIDE, rowbase, wt2, 256, 128, colbase, 128, acc, lane);
  epilogue<4>(acc, Pbuf, rowbase, colbase, b2, true, lane);
  __syncthreads();

  // L3: P @ W3 -> A (h3, kept for sigma)
  ZACC4();
  mfma_gb<4>(Pbuf, ASTRIDE, rowbase, wt3, 128, 0, colbase, 128, acc, lane);
  epilogue<4>(acc, Abuf, rowbase, colbase, b3, true, lane);
  __syncthreads();

  // Wf: A(h3) @ Wf -> P (no relu)
  ZACC4();
  mfma_gb<4>(Abuf, ASTRIDE, rowbase, wtf, 128, 0, colbase, 128, acc, lane);
  epilogue<4>(acc, Pbuf, rowbase, colbase, bfb, false, lane);
  __syncthreads();

  // Wd: [P(final) | D(dir)] @ Wd -> Q[:,0:64] (relu), N = 64
  int colbase_d = (wave & 1) * 32;
  ZACC4();
  mfma_gb<2>(Pbuf, ASTRIDE, rowbase, wtd, 160, 0,   colbase_d, 128, acc, lane);
  mfma_gb<2>(Dbuf, DSTRIDE, rowbase, wtd, 160, 128, colbase_d,  32, acc, lane);
  epilogue<2>(acc, Qbuf, rowbase, colbase_d, bdb, true, lane);
  __syncthreads();

  // Tail: sigma = h3(Abuf).Ws + bs ; rgb = d(Qbuf).Wr + br
  {
    int q = tid >> 3, part = tid & 7;
    float s = 0.f;
#pragma unroll
    for (int k = 0; k < 16; k++){
      int kk = part*16 + k;
      s = fmaf((float)Abuf[q*ASTRIDE + kk], Wsb[kk], s);
    }
    s += __shfl_xor(s, 1, 64); s += __shfl_xor(s, 2, 64); s += __shfl_xor(s, 4, 64);

    float r3[3];
#pragma unroll
    for (int c2 = 0; c2 < 3; c2++){
      float rv = 0.f;
#pragma unroll
      for (int k = 0; k < 8; k++){
        int kk = part*8 + k;
        rv = fmaf((float)Qbuf[q*ASTRIDE + kk], Wrb[kk*3 + c2], rv);
      }
      rv += __shfl_xor(rv, 1, 64); rv += __shfl_xor(rv, 2, 64); rv += __shfl_xor(rv, 4, 64);
      r3[c2] = rv;
    }
    if (part == 0){
      size_t ob = ((size_t)(qbase + q)) * 4;
      out[ob + 0] = r3[0] + brb[0];
      out[ob + 1] = r3[1] + brb[1];
      out[ob + 2] = r3[2] + brb[2];
      out[ob + 3] = s + bsb[0];
    }
  }
}

// ---------------------------------------------------------------------------
extern "C" void kernel_launch(void* const* d_in, const int* in_sizes, int n_in,
                              void* d_out, int out_size, void* d_ws, size_t ws_size,
                              hipStream_t stream){
  (void)in_sizes; (void)n_in; (void)out_size; (void)ws_size;

  const int*   indices = (const int*)d_in[0];
  const float* qpts    = (const float*)d_in[1];
  const float* xyzdir  = (const float*)d_in[2];
  const float* cpos    = (const float*)d_in[3];
  const float* codes   = (const float*)d_in[4];
  const float* W0 = (const float*)d_in[5];
  const float* b0 = (const float*)d_in[6];
  const float* W1 = (const float*)d_in[7];
  const float* b1 = (const float*)d_in[8];
  const float* W2 = (const float*)d_in[9];
  const float* b2 = (const float*)d_in[10];
  const float* W3 = (const float*)d_in[11];
  const float* b3 = (const float*)d_in[12];
  const float* Wf = (const float*)d_in[13];
  const float* bf = (const float*)d_in[14];
  const float* Wd = (const float*)d_in[15];
  const float* bd = (const float*)d_in[16];
  const float* Ws = (const float*)d_in[17];
  const float* bs = (const float*)d_in[18];
  const float* Wr = (const float*)d_in[19];
  const float* br = (const float*)d_in[20];

  float*  qcw   = (float*)d_ws;                                      // 16 MB
  half_t* wt    = (half_t*)((char*)d_ws + (size_t)N_Q*CDIM*4);       // 217088 B
  float4* cpos4 = (float4*)((char*)d_ws + (size_t)N_Q*CDIM*4 + 217088);

  wtrans_kernel<<<(110592 + 255)/256, 256, 0, stream>>>(W0, W1, W2, W3, Wf, Wd,
                                                        indices, cpos, wt, cpos4);
  knn_kernel<<<N_Q/8, 512, 0, stream>>>(indices, qpts, cpos4, codes, qcw);
  mlp_mfma<<<N_Q/32, 256, 0, stream>>>(qcw, xyzdir, wt,
                                       b0, b1, b2, b3, bf, bd, Ws, bs, Wr, br,
                                       (float*)d_out);
}

// Round 8
// 243.129 us; speedup vs baseline: 13.7992x; 1.2642x over previous
//
#include <hip/hip_runtime.h>

#define N_Q   65536
#define N_C   2048
#define KNN_K 16
#define CDIM  64
#define SLCAP 64
#define KINF  0x7FFFFFFF

typedef _Float16 half_t;
typedef float v4f __attribute__((ext_vector_type(4)));
typedef half_t v8h __attribute__((ext_vector_type(8)));

#define ASTRIDE 136   // 128 + 8 pad (halves); row = 272 B = 17*16 B
#define DSTRIDE 40    // 32 + 8 pad

// ---------------------------------------------------------------------------
// Kernel 0: weights -> fp16 MFMA-fragment-order tiles, plus cpos4.
// Tile (16 cols x 32 k) = 512 contiguous halves; element = lane*8 + j where
// lane = (n&15) + 16*quad, k = k0*32 + quad*8 + j. Layer layout:
// tiles ordered [k0chunk][tcol], nt = Ncols/16 tiles per k-chunk.
//  wt0 @ 0      (nt=8, K=128; k==127 -> 0)        W0 (127,128)
//  wt1 @ 16384  (nt=8, K=128)                      W1 (128,128)
//  wt2 @ 32768  (nt=8, K=256; k==127->0, k>=128 -> W2[k-1])  W2 (255,128)
//  wt3 @ 65536  (nt=8, K=128)                      W3 (128,128)
//  wtf @ 81920  (nt=8, K=128)                      Wf (128,128)
//  wtd @ 98304  (nt=4, K=160; k>=155 -> 0)         Wd (155,64)
// total 108544 halves; cpos4[2048] after.
// ---------------------------------------------------------------------------
__global__ void wtrans_kernel(const float* W0, const float* W1, const float* W2,
                              const float* W3, const float* Wf, const float* Wd,
                              const int* indices, const float* cpos,
                              half_t* wt, float4* cpos4){
  int idx = blockIdx.x * 256 + threadIdx.x;
  if (idx >= 110592) return;
  if (idx >= 108544){
    int i = idx - 108544;
    const float* cp = cpos + (size_t)indices[0] * N_C * 3;
    float x = cp[i*3 + 0], y = cp[i*3 + 1], z = cp[i*3 + 2];
    cpos4[i] = make_float4(x, y, z, fmaf(x, x, fmaf(y, y, fmaf(z, z, 4.0f))));
    return;
  }
  int base, nt, mode;            // mode: 0 plain(src), 1 W0, 2 W2, 3 Wd
  const float* src = W1;
  if (idx < 16384){ base = 0; nt = 8; mode = 1; }
  else if (idx < 32768){ base = 16384; nt = 8; mode = 0; src = W1; }
  else if (idx < 65536){ base = 32768; nt = 8; mode = 2; }
  else if (idx < 81920){ base = 65536; nt = 8; mode = 0; src = W3; }
  else if (idx < 98304){ base = 81920; nt = 8; mode = 0; src = Wf; }
  else { base = 98304; nt = 4; mode = 3; }
  int i = idx - base;
  int tile = i >> 9, e = i & 511;
  int lane = e >> 3, j = e & 7;
  int k0idx = tile / nt, tcol = tile - k0idx*nt;
  int n = tcol*16 + (lane & 15);
  int k = k0idx*32 + ((lane >> 4) << 3) + j;
  float val;
  if (mode == 0)      val = src[k*128 + n];
  else if (mode == 1) val = (k < 127) ? W0[k*128 + n] : 0.f;
  else if (mode == 2) val = (k == 127) ? 0.f
                           : ((k < 127) ? W2[k*128 + n] : W2[(k-1)*128 + n]);
  else                val = (k < 155) ? Wd[k*64 + n] : 0.f;
  wt[idx] = (half_t)val;
}

// ---------------------------------------------------------------------------
// Kernel 0b: pre-stage xyzdir into padded fp16 rows.
// Ain[q][64..135]: cols 64..126 = xyzdir[q][0..62], 127..135 = 0.
// Din[q][0..39]  : cols 0..26   = xyzdir[q][63..89], 27..39 = 0.
// (Ain cols 0..63 are written by knn_kernel.)
// ---------------------------------------------------------------------------
__global__ void prep_kernel(const float* xyzdir, half_t* Ain, half_t* Din){
  int idx = blockIdx.x * 256 + threadIdx.x;
  if (idx < N_Q*72){
    int q = idx / 72, c = idx - q*72 + 64;
    float v = (c < 127) ? xyzdir[(size_t)q*90 + (c - 64)] : 0.f;
    Ain[(size_t)q*ASTRIDE + c] = (half_t)v;
  } else {
    int i2 = idx - N_Q*72;
    if (i2 >= N_Q*40) return;
    int q = i2 / 40, c = i2 - q*40;
    float v = (c < 27) ? xyzdir[(size_t)q*90 + 63 + c] : 0.f;
    Din[(size_t)q*DSTRIDE + c] = (half_t)v;
  }
}

// ---------------------------------------------------------------------------
// Kernel 1: exact 16-NN, tau-pruned (unchanged structure from round 7).
// Writes query_codes as fp16 directly into Ain[q][0..63].
// ---------------------------------------------------------------------------
__global__ __launch_bounds__(512, 8) void knn_kernel(const int* indices,
    const float* qpts, const float4* cpos4, const float* codes, half_t* Ain){
  __shared__ float4 lp[N_C];        // 32 KB
  __shared__ int    sl[8*SLCAP];    // 2 KB
  int tid = threadIdx.x;
  int lane = tid & 63, wave = tid >> 6;
  const float* cc = codes + (size_t)indices[0] * N_C * CDIM;

  for (int c = tid; c < N_C; c += 512) lp[c] = cpos4[c];
  __syncthreads();

  int q = blockIdx.x * 8 + wave;
  float qx = qpts[q*3 + 0];
  float qy = qpts[q*3 + 1];
  float qz = qpts[q*3 + 2];
  float nqx = -2.0f*qx, nqy = -2.0f*qy, nqz = -2.0f*qz;

  int p[32];
#pragma unroll
  for (int j = 0; j < 32; j++){
    int c = j*64 + lane;
    float4 P = lp[c];
    float s = fmaf(P.x, nqx, fmaf(P.y, nqy, fmaf(P.z, nqz, P.w)));  // > 0
    p[j] = (__float_as_int(s) & 0xFFFFF800) | c;
  }

  int lm = p[0];
#pragma unroll
  for (int j = 1; j < 32; j++) lm = min(lm, p[j]);

  int v = lm;
#pragma unroll
  for (int k = 2; k <= 64; k <<= 1){
#pragma unroll
    for (int j = k >> 1; j > 0; j >>= 1){
      int o = __shfl_xor(v, j, 64);
      bool dirDesc = (lane & k) != 0;
      bool lower   = (lane & j) == 0;
      int mn = min(v, o), mx = max(v, o);
      v = (lower != dirDesc) ? mn : mx;
    }
  }
  int tau = __shfl(v, 15, 64);

  int cnt = 0;
#pragma unroll
  for (int j = 0; j < 32; j++) cnt += (p[j] <= tau) ? 1 : 0;
  int incl = cnt;
#pragma unroll
  for (int d = 1; d < 64; d <<= 1){
    int t = __shfl_up(incl, d, 64);
    incl += (lane >= d) ? t : 0;
  }
  int n = __shfl(incl, 63, 64);
  int base = incl - cnt;

  int keep = 0;
  if (n >= KNN_K && n <= SLCAP){
    int* slw = &sl[wave * SLCAP];
    int off = base;
#pragma unroll
    for (int j = 0; j < 32; j++){
      if (p[j] <= tau){ slw[off] = p[j]; off++; }
    }
    __builtin_amdgcn_wave_barrier();

    int x = (lane < n) ? slw[lane] : KINF;
#pragma unroll
    for (int k = 2; k <= 64; k <<= 1){
#pragma unroll
      for (int j = k >> 1; j > 0; j >>= 1){
        int o = __shfl_xor(x, j, 64);
        bool dirDesc = (lane & k) != 0;
        bool lower   = (lane & j) == 0;
        int mn = min(x, o), mx = max(x, o);
        x = (lower != dirDesc) ? mn : mx;
      }
    }
    keep = x;
  } else {
#pragma unroll 1
    for (int rr = 0; rr < KNN_K; rr++){
      int lmf = p[0];
#pragma unroll
      for (int j = 1; j < 32; j++) lmf = min(lmf, p[j]);
      int gm = lmf;
#pragma unroll
      for (int off2 = 1; off2 < 64; off2 <<= 1)
        gm = min(gm, __shfl_xor(gm, off2, 64));
      if (lane == rr) keep = gm;
#pragma unroll
      for (int j = 0; j < 32; j++) p[j] = (p[j] == gm) ? KINF : p[j];
    }
  }

  int ci = keep & 0x7FF;
  float4 P = lp[ci];
  float dx = qx - P.x, dy = qy - P.y, dz = qz - P.z;
  float d2 = fmaf(dz, dz, fmaf(dy, dy, dx*dx));
  float w = 1.0f / (d2 + 1e-16f);
  float wm = (lane < KNN_K) ? w : 0.0f;
#pragma unroll
  for (int off2 = 1; off2 < 64; off2 <<= 1) wm += __shfl_xor(wm, off2, 64);
  float wn = w / wm;

  float acc = 0.f;
#pragma unroll
  for (int i = 0; i < KNN_K; i++){
    int   cb = __shfl(ci, i, 64);
    float wb = __shfl(wn, i, 64);
    acc = fmaf(wb, cc[cb*CDIM + lane], acc);
  }
  Ain[(size_t)q*ASTRIDE + lane] = (half_t)acc;
}

// ---------------------------------------------------------------------------
// Kernel 2: fused MFMA MLP, B-fragments from global in fragment order:
// one coalesced 1 KB load per 16x32 tile (lane*16B). 32 queries/block.
// ---------------------------------------------------------------------------
template<int NT>
__device__ inline void mfma_sw(const half_t* act, int astride, int rowbase,
                               const half_t* wlayer, int nt, int ktbase,
                               int tcolbase, int kchunk, v4f* acc, int lane){
  int m = lane & 15, quad = lane >> 4;
#pragma unroll
  for (int k0 = 0; k0 < kchunk; k0 += 32){
    v8h a = *(const v8h*)&act[(rowbase + m)*astride + k0 + quad*8];
    int krow = ktbase + (k0 >> 5);
#pragma unroll
    for (int t = 0; t < NT; t++){
      const half_t* bp = wlayer + ((size_t)((krow*nt + tcolbase + t) << 9) + (lane << 3));
      v8h b = *(const v8h*)bp;
      acc[t] = __builtin_amdgcn_mfma_f32_16x16x32_f16(a, b, acc[t], 0, 0, 0);
    }
  }
}

template<int NT>
__device__ inline void epilogue(v4f* acc, half_t* outb, int rowbase, int colbase,
                                const float* bias, bool relu, int lane){
  int n = lane & 15, quad = lane >> 4;
#pragma unroll
  for (int t = 0; t < NT; t++){
    int col = colbase + t*16 + n;
    float bv = bias[col];
#pragma unroll
    for (int r = 0; r < 4; r++){
      float v = acc[t][r] + bv;
      if (relu) v = fmaxf(v, 0.f);
      outb[(rowbase + quad*4 + r)*ASTRIDE + col] = (half_t)v;
    }
  }
}

__global__ __launch_bounds__(256) void mlp_mfma(
    const half_t* Ain, const half_t* Din, const half_t* wt,
    const float* b0, const float* b1, const float* b2, const float* b3,
    const float* bfb, const float* bdb,
    const float* Wsb, const float* bsb, const float* Wrb, const float* brb,
    float* out){
  __shared__ __align__(16) half_t Abuf[32*ASTRIDE];
  __shared__ __align__(16) half_t Pbuf[32*ASTRIDE];
  __shared__ __align__(16) half_t Qbuf[32*ASTRIDE];
  __shared__ __align__(16) half_t Dbuf[32*DSTRIDE];

  int tid = threadIdx.x, lane = tid & 63, wave = tid >> 6;
  int qbase = blockIdx.x * 32;

  // coalesced 16-B staging of pre-built fp16 activations
  for (int i = tid; i < 32*17; i += 256){
    int r = i / 17, c8 = i - r*17;
    *(uint4*)&Abuf[r*ASTRIDE + (c8 << 3)] =
        *(const uint4*)&Ain[(size_t)(qbase + r)*ASTRIDE + (c8 << 3)];
  }
  for (int i = tid; i < 32*5; i += 256){
    int r = i / 5, c8 = i - r*5;
    *(uint4*)&Dbuf[r*DSTRIDE + (c8 << 3)] =
        *(const uint4*)&Din[(size_t)(qbase + r)*DSTRIDE + (c8 << 3)];
  }
  __syncthreads();

  int rowbase = (wave >> 1) * 16;
  int colhalf = wave & 1;
  int colbase = colhalf * 64;
  int tcolbase = colhalf * 4;
  v4f acc[4];

  const half_t* wt0 = wt;
  const half_t* wt1 = wt + 16384;
  const half_t* wt2 = wt + 32768;
  const half_t* wt3 = wt + 65536;
  const half_t* wtf = wt + 81920;
  const half_t* wtd = wt + 98304;

#define ZACC4() { for (int t_ = 0; t_ < 4; t_++) for (int e_ = 0; e_ < 4; e_++) acc[t_][e_] = 0.f; }

  // L0: A @ W0 -> P (relu)
  ZACC4();
  mfma_sw<4>(Abuf, ASTRIDE, rowbase, wt0, 8, 0, tcolbase, 128, acc, lane);
  epilogue<4>(acc, Pbuf, rowbase, colbase, b0, true, lane);
  __syncthreads();

  // L1: P @ W1 -> Q (relu)
  ZACC4();
  mfma_sw<4>(Pbuf, ASTRIDE, rowbase, wt1, 8, 0, tcolbase, 128, acc, lane);
  epilogue<4>(acc, Qbuf, rowbase, colbase, b1, true, lane);
  __syncthreads();

  // L2: [input_xyz | h1] @ W2 -> P (relu)   (K = 256)
  ZACC4();
  mfma_sw<4>(Abuf, ASTRIDE, rowbase, wt2, 8, 0, tcolbase, 128, acc, lane);
  mfma_sw<4>(Qbuf, ASTRIDE, rowbase, wt2, 8, 4, tcolbase, 128, acc, lane);
  epilogue<4>(acc, Pbuf, rowbase, colbase, b2, true, lane);
  __syncthreads();

  // L3: P @ W3 -> A (h3, kept for sigma)
  ZACC4();
  mfma_sw<4>(Pbuf, ASTRIDE, rowbase, wt3, 8, 0, tcolbase, 128, acc, lane);
  epilogue<4>(acc, Abuf, rowbase, colbase, b3, true, lane);
  __syncthreads();

  // Wf: A(h3) @ Wf -> P (no relu)
  ZACC4();
  mfma_sw<4>(Abuf, ASTRIDE, rowbase, wtf, 8, 0, tcolbase, 128, acc, lane);
  epilogue<4>(acc, Pbuf, rowbase, colbase, bfb, false, lane);
  __syncthreads();

  // Wd: [P(final) | D(dir)] @ Wd -> Q[:,0:64] (relu), N = 64, nt = 4
  int tcolbase_d = colhalf * 2;
  int colbase_d  = colhalf * 32;
  ZACC4();
  mfma_sw<2>(Pbuf, ASTRIDE, rowbase, wtd, 4, 0, tcolbase_d, 128, acc, lane);
  mfma_sw<2>(Dbuf, DSTRIDE, rowbase, wtd, 4, 4, tcolbase_d,  32, acc, lane);
  epilogue<2>(acc, Qbuf, rowbase, colbase_d, bdb, true, lane);
  __syncthreads();

  // Tail: sigma = h3(Abuf).Ws + bs ; rgb = d(Qbuf).Wr + br
  {
    int q = tid >> 3, part = tid & 7;
    float s = 0.f;
#pragma unroll
    for (int k = 0; k < 16; k++){
      int kk = part*16 + k;
      s = fmaf((float)Abuf[q*ASTRIDE + kk], Wsb[kk], s);
    }
    s += __shfl_xor(s, 1, 64); s += __shfl_xor(s, 2, 64); s += __shfl_xor(s, 4, 64);

    float r3[3];
#pragma unroll
    for (int c2 = 0; c2 < 3; c2++){
      float rv = 0.f;
#pragma unroll
      for (int k = 0; k < 8; k++){
        int kk = part*8 + k;
        rv = fmaf((float)Qbuf[q*ASTRIDE + kk], Wrb[kk*3 + c2], rv);
      }
      rv += __shfl_xor(rv, 1, 64); rv += __shfl_xor(rv, 2, 64); rv += __shfl_xor(rv, 4, 64);
      r3[c2] = rv;
    }
    if (part == 0){
      size_t ob = ((size_t)(qbase + q)) * 4;
      out[ob + 0] = r3[0] + brb[0];
      out[ob + 1] = r3[1] + brb[1];
      out[ob + 2] = r3[2] + brb[2];
      out[ob + 3] = s + bsb[0];
    }
  }
}

// ---------------------------------------------------------------------------
extern "C" void kernel_launch(void* const* d_in, const int* in_sizes, int n_in,
                              void* d_out, int out_size, void* d_ws, size_t ws_size,
                              hipStream_t stream){
  (void)in_sizes; (void)n_in; (void)out_size; (void)ws_size;

  const int*   indices = (const int*)d_in[0];
  const float* qpts    = (const float*)d_in[1];
  const float* xyzdir  = (const float*)d_in[2];
  const float* cpos    = (const float*)d_in[3];
  const float* codes   = (const float*)d_in[4];
  const float* W0 = (const float*)d_in[5];
  const float* b0 = (const float*)d_in[6];
  const float* W1 = (const float*)d_in[7];
  const float* b1 = (const float*)d_in[8];
  const float* W2 = (const float*)d_in[9];
  const float* b2 = (const float*)d_in[10];
  const float* W3 = (const float*)d_in[11];
  const float* b3 = (const float*)d_in[12];
  const float* Wf = (const float*)d_in[13];
  const float* bf = (const float*)d_in[14];
  const float* Wd = (const float*)d_in[15];
  const float* bd = (const float*)d_in[16];
  const float* Ws = (const float*)d_in[17];
  const float* bs = (const float*)d_in[18];
  const float* Wr = (const float*)d_in[19];
  const float* br = (const float*)d_in[20];

  // ws layout (16-B aligned): Ain | Din | wt | cpos4
  half_t* Ain   = (half_t*)d_ws;                                   // 17,825,792 B
  half_t* Din   = (half_t*)((char*)d_ws + 17825792);               //  5,242,880 B
  half_t* wt    = (half_t*)((char*)d_ws + 17825792 + 5242880);     //    217,088 B
  float4* cpos4 = (float4*)((char*)d_ws + 17825792 + 5242880 + 217088);

  wtrans_kernel<<<(110592 + 255)/256, 256, 0, stream>>>(W0, W1, W2, W3, Wf, Wd,
                                                        indices, cpos, wt, cpos4);
  prep_kernel<<<(N_Q*112 + 255)/256, 256, 0, stream>>>(xyzdir, Ain, Din);
  knn_kernel<<<N_Q/8, 512, 0, stream>>>(indices, qpts, cpos4, codes, Ain);
  mlp_mfma<<<N_Q/32, 256, 0, stream>>>(Ain, Din, wt,
                                       b0, b1, b2, b3, bf, bd, Ws, bs, Wr, br,
                                       (float*)d_out);
}

// Round 9
// 231.962 us; speedup vs baseline: 14.4635x; 1.0481x over previous
//
#include <hip/hip_runtime.h>

#define N_Q   65536
#define N_C   2048
#define KNN_K 16
#define CDIM  64
#define SLCAP 128     // survivor list capacity (overflow -> exact fallback)
#define KINF  0x7FFFFFFF

typedef _Float16 half_t;
typedef float v4f __attribute__((ext_vector_type(4)));
typedef half_t v8h __attribute__((ext_vector_type(8)));

#define ASTRIDE 136   // 128 + 8 pad (halves); row = 272 B = 17*16 B
#define DSTRIDE 40    // 32 + 8 pad

// ---------------------------------------------------------------------------
// Kernel 0: weights -> fp16 MFMA-fragment-order tiles, plus cpos4.
// (unchanged from round 8)
// ---------------------------------------------------------------------------
__global__ void wtrans_kernel(const float* W0, const float* W1, const float* W2,
                              const float* W3, const float* Wf, const float* Wd,
                              const int* indices, const float* cpos,
                              half_t* wt, float4* cpos4){
  int idx = blockIdx.x * 256 + threadIdx.x;
  if (idx >= 110592) return;
  if (idx >= 108544){
    int i = idx - 108544;
    const float* cp = cpos + (size_t)indices[0] * N_C * 3;
    float x = cp[i*3 + 0], y = cp[i*3 + 1], z = cp[i*3 + 2];
    cpos4[i] = make_float4(x, y, z, fmaf(x, x, fmaf(y, y, fmaf(z, z, 4.0f))));
    return;
  }
  int base, nt, mode;            // mode: 0 plain(src), 1 W0, 2 W2, 3 Wd
  const float* src = W1;
  if (idx < 16384){ base = 0; nt = 8; mode = 1; }
  else if (idx < 32768){ base = 16384; nt = 8; mode = 0; src = W1; }
  else if (idx < 65536){ base = 32768; nt = 8; mode = 2; }
  else if (idx < 81920){ base = 65536; nt = 8; mode = 0; src = W3; }
  else if (idx < 98304){ base = 81920; nt = 8; mode = 0; src = Wf; }
  else { base = 98304; nt = 4; mode = 3; }
  int i = idx - base;
  int tile = i >> 9, e = i & 511;
  int lane = e >> 3, j = e & 7;
  int k0idx = tile / nt, tcol = tile - k0idx*nt;
  int n = tcol*16 + (lane & 15);
  int k = k0idx*32 + ((lane >> 4) << 3) + j;
  float val;
  if (mode == 0)      val = src[k*128 + n];
  else if (mode == 1) val = (k < 127) ? W0[k*128 + n] : 0.f;
  else if (mode == 2) val = (k == 127) ? 0.f
                           : ((k < 127) ? W2[k*128 + n] : W2[(k-1)*128 + n]);
  else                val = (k < 155) ? Wd[k*64 + n] : 0.f;
  wt[idx] = (half_t)val;
}

// ---------------------------------------------------------------------------
// Kernel 1: exact 16-NN + activation staging. One WAVE per query (8/block).
// Key = (score_bits & ~0x7FF) | c, score = |c|^2+4 - 2 q.c  (> 0).
// tau: sort lane-mins within 16-lane groups (10 stages); tau = max of the 4
//   groups' 4th-smallest -> #{keys<=tau} >= 16 GUARANTEED (4 distinct per
//   group). Ballot-compact survivors (scalar n, mbcnt positions).
// n<=64: top-16-of-64 bitonic selection network (10+1+4+1 stages) -> lanes
//   0..15 hold the exact top-16 SET (order irrelevant: weighted sum is
//   symmetric). Else: exact full-rescan fallback.
// Also writes xyzdir into Ain[64..135] / Din (prep kernel folded in).
// ---------------------------------------------------------------------------
__global__ __launch_bounds__(512, 8) void knn_kernel(const int* indices,
    const float* qpts, const float4* cpos4, const float* codes,
    const float* xyzdir, half_t* Ain, half_t* Din){
  __shared__ float4 lp[N_C];        // 32 KB
  __shared__ int    sl[8*SLCAP];    // 4 KB
  int tid = threadIdx.x;
  int lane = tid & 63, wave = tid >> 6;
  int l = lane & 15;                // lane within 16-group
  const float* cc = codes + (size_t)indices[0] * N_C * CDIM;

  for (int c = tid; c < N_C; c += 512) lp[c] = cpos4[c];
  __syncthreads();

  int q = blockIdx.x * 8 + wave;
  float qx = qpts[q*3 + 0];
  float qy = qpts[q*3 + 1];
  float qz = qpts[q*3 + 2];
  float nqx = -2.0f*qx, nqy = -2.0f*qy, nqz = -2.0f*qz;

  int p[32];
#pragma unroll
  for (int j = 0; j < 32; j++){
    int c = j*64 + lane;
    float4 P = lp[c];
    float s = fmaf(P.x, nqx, fmaf(P.y, nqy, fmaf(P.z, nqz, P.w)));  // > 0
    p[j] = (__float_as_int(s) & 0xFFFFF800) | c;
  }

  // lane-local min
  int lm = p[0];
#pragma unroll
  for (int j = 1; j < 32; j++) lm = min(lm, p[j]);

  // sort lane-mins ascending WITHIN each 16-lane group (10 stages)
  int v = lm;
#pragma unroll
  for (int k = 2; k <= 16; k <<= 1){
#pragma unroll
    for (int j = k >> 1; j > 0; j >>= 1){
      int o = __shfl_xor(v, j, 64);
      bool dirDesc = (l & k) != 0;       // k=16 -> ascending in every group
      bool lower   = (l & j) == 0;
      int mn = min(v, o), mx = max(v, o);
      v = (lower != dirDesc) ? mn : mx;
    }
  }
  // tau = max over groups of group's 4th-smallest (local lane 3)
  int t0 = __shfl(v, 3, 64),  t1 = __shfl(v, 19, 64);
  int t2 = __shfl(v, 35, 64), t3 = __shfl(v, 51, 64);
  int tau = max(max(t0, t1), max(t2, t3));

  // ballot-compaction: scalar running n, per-lane position via mbcnt
  int* slw = &sl[wave * SLCAP];
  int n = 0;
#pragma unroll
  for (int j = 0; j < 32; j++){
    bool c = (p[j] <= tau);
    unsigned long long m = __ballot(c);
    if (m){
      if (n <= 64){                      // cap writes; n>64 -> fallback anyway
        if (c){
          int mb = __builtin_amdgcn_mbcnt_hi((unsigned)(m >> 32),
                   __builtin_amdgcn_mbcnt_lo((unsigned)m, 0));
          slw[n + mb] = p[j];
        }
      }
      n += (int)__popcll(m);
    }
  }
  __builtin_amdgcn_wave_barrier();

  int keep;
  if (n >= KNN_K && n <= 64){
    // top-16-of-64 selection network -> lanes 0..15 hold the top-16 set
    int x = (lane < n) ? slw[lane] : KINF;
    // sort-16 ascending (10 stages)
#pragma unroll
    for (int k = 2; k <= 16; k <<= 1){
#pragma unroll
      for (int j = k >> 1; j > 0; j >>= 1){
        int o = __shfl_xor(x, j, 64);
        bool dirDesc = (l & k) != 0;
        bool lower   = (l & j) == 0;
        int mn = min(x, o), mx = max(x, o);
        x = (lower != dirDesc) ? mn : mx;
      }
    }
    // mirror-min across each 32 (bitonic split: keeps bottom-16 of 32)
    x = min(x, __shfl_xor(x, 31, 64));
    // re-sort the bitonic 16-seq ascending (4 stages)
#pragma unroll
    for (int j = 8; j > 0; j >>= 1){
      int o = __shfl_xor(x, j, 64);
      bool lower = (l & j) == 0;
      int mn = min(x, o), mx = max(x, o);
      x = lower ? mn : mx;
    }
    // mirror-min across 64: bottom-16 of all 64, one per lane in each group
    x = min(x, __shfl_xor(x, 63, 64));
    keep = x;
  } else {
    // exact fallback: full rescan extraction over p[32] (rare)
    keep = KINF;
#pragma unroll 1
    for (int rr = 0; rr < KNN_K; rr++){
      int lmf = p[0];
#pragma unroll
      for (int j = 1; j < 32; j++) lmf = min(lmf, p[j]);
      int gm = lmf;
#pragma unroll
      for (int off2 = 1; off2 < 64; off2 <<= 1)
        gm = min(gm, __shfl_xor(gm, off2, 64));
      if (lane == rr) keep = gm;
#pragma unroll
      for (int j = 0; j < 32; j++) p[j] = (p[j] == gm) ? KINF : p[j];
    }
  }

  // exact d2 + inverse-d2 weights (lanes 0..15 meaningful)
  int ci = keep & 0x7FF;
  float4 P = lp[ci];
  float dx = qx - P.x, dy = qy - P.y, dz = qz - P.z;
  float d2 = fmaf(dz, dz, fmaf(dy, dy, dx*dx));
  float w = 1.0f / (d2 + 1e-16f);
  float wm = (lane < KNN_K) ? w : 0.0f;
#pragma unroll
  for (int off2 = 1; off2 < 64; off2 <<= 1) wm += __shfl_xor(wm, off2, 64);
  float wn = w / wm;

  float acc = 0.f;
#pragma unroll
  for (int i = 0; i < KNN_K; i++){
    int   cb = __shfl(ci, i, 64);
    float wb = __shfl(wn, i, 64);
    acc = fmaf(wb, cc[cb*CDIM + lane], acc);
  }
  size_t arow = (size_t)q * ASTRIDE;
  Ain[arow + lane] = (half_t)acc;

  // folded prep: xyzdir -> Ain cols 64..127 (lane 63 writes the 0 pad), pads
  float xv = (lane < 63) ? xyzdir[(size_t)q*90 + lane] : 0.f;
  Ain[arow + 64 + lane] = (half_t)xv;
  if (lane < 8) Ain[arow + 128 + lane] = (half_t)0.f;
  if (lane < 40){
    float dv = (lane < 27) ? xyzdir[(size_t)q*90 + 63 + lane] : 0.f;
    Din[(size_t)q*DSTRIDE + lane] = (half_t)dv;
  }
}

// ---------------------------------------------------------------------------
// Kernel 2: fused MFMA MLP (unchanged from round 8).
// ---------------------------------------------------------------------------
template<int NT>
__device__ inline void mfma_sw(const half_t* act, int astride, int rowbase,
                               const half_t* wlayer, int nt, int ktbase,
                               int tcolbase, int kchunk, v4f* acc, int lane){
  int m = lane & 15, quad = lane >> 4;
#pragma unroll
  for (int k0 = 0; k0 < kchunk; k0 += 32){
    v8h a = *(const v8h*)&act[(rowbase + m)*astride + k0 + quad*8];
    int krow = ktbase + (k0 >> 5);
#pragma unroll
    for (int t = 0; t < NT; t++){
      const half_t* bp = wlayer + ((size_t)((krow*nt + tcolbase + t) << 9) + (lane << 3));
      v8h b = *(const v8h*)bp;
      acc[t] = __builtin_amdgcn_mfma_f32_16x16x32_f16(a, b, acc[t], 0, 0, 0);
    }
  }
}

template<int NT>
__device__ inline void epilogue(v4f* acc, half_t* outb, int rowbase, int colbase,
                                const float* bias, bool relu, int lane){
  int n = lane & 15, quad = lane >> 4;
#pragma unroll
  for (int t = 0; t < NT; t++){
    int col = colbase + t*16 + n;
    float bv = bias[col];
#pragma unroll
    for (int r = 0; r < 4; r++){
      float v = acc[t][r] + bv;
      if (relu) v = fmaxf(v, 0.f);
      outb[(rowbase + quad*4 + r)*ASTRIDE + col] = (half_t)v;
    }
  }
}

__global__ __launch_bounds__(256) void mlp_mfma(
    const half_t* Ain, const half_t* Din, const half_t* wt,
    const float* b0, const float* b1, const float* b2, const float* b3,
    const float* bfb, const float* bdb,
    const float* Wsb, const float* bsb, const float* Wrb, const float* brb,
    float* out){
  __shared__ __align__(16) half_t Abuf[32*ASTRIDE];
  __shared__ __align__(16) half_t Pbuf[32*ASTRIDE];
  __shared__ __align__(16) half_t Qbuf[32*ASTRIDE];
  __shared__ __align__(16) half_t Dbuf[32*DSTRIDE];

  int tid = threadIdx.x, lane = tid & 63, wave = tid >> 6;
  int qbase = blockIdx.x * 32;

  for (int i = tid; i < 32*17; i += 256){
    int r = i / 17, c8 = i - r*17;
    *(uint4*)&Abuf[r*ASTRIDE + (c8 << 3)] =
        *(const uint4*)&Ain[(size_t)(qbase + r)*ASTRIDE + (c8 << 3)];
  }
  for (int i = tid; i < 32*5; i += 256){
    int r = i / 5, c8 = i - r*5;
    *(uint4*)&Dbuf[r*DSTRIDE + (c8 << 3)] =
        *(const uint4*)&Din[(size_t)(qbase + r)*DSTRIDE + (c8 << 3)];
  }
  __syncthreads();

  int rowbase = (wave >> 1) * 16;
  int colhalf = wave & 1;
  int colbase = colhalf * 64;
  int tcolbase = colhalf * 4;
  v4f acc[4];

  const half_t* wt0 = wt;
  const half_t* wt1 = wt + 16384;
  const half_t* wt2 = wt + 32768;
  const half_t* wt3 = wt + 65536;
  const half_t* wtf = wt + 81920;
  const half_t* wtd = wt + 98304;

#define ZACC4() { for (int t_ = 0; t_ < 4; t_++) for (int e_ = 0; e_ < 4; e_++) acc[t_][e_] = 0.f; }

  // L0: A @ W0 -> P (relu)
  ZACC4();
  mfma_sw<4>(Abuf, ASTRIDE, rowbase, wt0, 8, 0, tcolbase, 128, acc, lane);
  epilogue<4>(acc, Pbuf, rowbase, colbase, b0, true, lane);
  __syncthreads();

  // L1: P @ W1 -> Q (relu)
  ZACC4();
  mfma_sw<4>(Pbuf, ASTRIDE, rowbase, wt1, 8, 0, tcolbase, 128, acc, lane);
  epilogue<4>(acc, Qbuf, rowbase, colbase, b1, true, lane);
  __syncthreads();

  // L2: [input_xyz | h1] @ W2 -> P (relu)   (K = 256)
  ZACC4();
  mfma_sw<4>(Abuf, ASTRIDE, rowbase, wt2, 8, 0, tcolbase, 128, acc, lane);
  mfma_sw<4>(Qbuf, ASTRIDE, rowbase, wt2, 8, 4, tcolbase, 128, acc, lane);
  epilogue<4>(acc, Pbuf, rowbase, colbase, b2, true, lane);
  __syncthreads();

  // L3: P @ W3 -> A (h3, kept for sigma)
  ZACC4();
  mfma_sw<4>(Pbuf, ASTRIDE, rowbase, wt3, 8, 0, tcolbase, 128, acc, lane);
  epilogue<4>(acc, Abuf, rowbase, colbase, b3, true, lane);
  __syncthreads();

  // Wf: A(h3) @ Wf -> P (no relu)
  ZACC4();
  mfma_sw<4>(Abuf, ASTRIDE, rowbase, wtf, 8, 0, tcolbase, 128, acc, lane);
  epilogue<4>(acc, Pbuf, rowbase, colbase, bfb, false, lane);
  __syncthreads();

  // Wd: [P(final) | D(dir)] @ Wd -> Q[:,0:64] (relu), N = 64, nt = 4
  int tcolbase_d = colhalf * 2;
  int colbase_d  = colhalf * 32;
  ZACC4();
  mfma_sw<2>(Pbuf, ASTRIDE, rowbase, wtd, 4, 0, tcolbase_d, 128, acc, lane);
  mfma_sw<2>(Dbuf, DSTRIDE, rowbase, wtd, 4, 4, tcolbase_d,  32, acc, lane);
  epilogue<2>(acc, Qbuf, rowbase, colbase_d, bdb, true, lane);
  __syncthreads();

  // Tail: sigma = h3(Abuf).Ws + bs ; rgb = d(Qbuf).Wr + br
  {
    int q = tid >> 3, part = tid & 7;
    float s = 0.f;
#pragma unroll
    for (int k = 0; k < 16; k++){
      int kk = part*16 + k;
      s = fmaf((float)Abuf[q*ASTRIDE + kk], Wsb[kk], s);
    }
    s += __shfl_xor(s, 1, 64); s += __shfl_xor(s, 2, 64); s += __shfl_xor(s, 4, 64);

    float r3[3];
#pragma unroll
    for (int c2 = 0; c2 < 3; c2++){
      float rv = 0.f;
#pragma unroll
      for (int k = 0; k < 8; k++){
        int kk = part*8 + k;
        rv = fmaf((float)Qbuf[q*ASTRIDE + kk], Wrb[kk*3 + c2], rv);
      }
      rv += __shfl_xor(rv, 1, 64); rv += __shfl_xor(rv, 2, 64); rv += __shfl_xor(rv, 4, 64);
      r3[c2] = rv;
    }
    if (part == 0){
      size_t ob = ((size_t)(qbase + q)) * 4;
      out[ob + 0] = r3[0] + brb[0];
      out[ob + 1] = r3[1] + brb[1];
      out[ob + 2] = r3[2] + brb[2];
      out[ob + 3] = s + bsb[0];
    }
  }
}

// ---------------------------------------------------------------------------
extern "C" void kernel_launch(void* const* d_in, const int* in_sizes, int n_in,
                              void* d_out, int out_size, void* d_ws, size_t ws_size,
                              hipStream_t stream){
  (void)in_sizes; (void)n_in; (void)out_size; (void)ws_size;

  const int*   indices = (const int*)d_in[0];
  const float* qpts    = (const float*)d_in[1];
  const float* xyzdir  = (const float*)d_in[2];
  const float* cpos    = (const float*)d_in[3];
  const float* codes   = (const float*)d_in[4];
  const float* W0 = (const float*)d_in[5];
  const float* b0 = (const float*)d_in[6];
  const float* W1 = (const float*)d_in[7];
  const float* b1 = (const float*)d_in[8];
  const float* W2 = (const float*)d_in[9];
  const float* b2 = (const float*)d_in[10];
  const float* W3 = (const float*)d_in[11];
  const float* b3 = (const float*)d_in[12];
  const float* Wf = (const float*)d_in[13];
  const float* bf = (const float*)d_in[14];
  const float* Wd = (const float*)d_in[15];
  const float* bd = (const float*)d_in[16];
  const float* Ws = (const float*)d_in[17];
  const float* bs = (const float*)d_in[18];
  const float* Wr = (const float*)d_in[19];
  const float* br = (const float*)d_in[20];

  // ws layout (16-B aligned): Ain | Din | wt | cpos4
  half_t* Ain   = (half_t*)d_ws;                                   // 17,825,792 B
  half_t* Din   = (half_t*)((char*)d_ws + 17825792);               //  5,242,880 B
  half_t* wt    = (half_t*)((char*)d_ws + 17825792 + 5242880);     //    217,088 B
  float4* cpos4 = (float4*)((char*)d_ws + 17825792 + 5242880 + 217088);

  wtrans_kernel<<<(110592 + 255)/256, 256, 0, stream>>>(W0, W1, W2, W3, Wf, Wd,
                                                        indices, cpos, wt, cpos4);
  knn_kernel<<<N_Q/8, 512, 0, stream>>>(indices, qpts, cpos4, codes, xyzdir,
                                        Ain, Din);
  mlp_mfma<<<N_Q/32, 256, 0, stream>>>(Ain, Din, wt,
                                       b0, b1, b2, b3, bf, bd, Ws, bs, Wr, br,
                                       (float*)d_out);
}